// Round 3
// baseline (798.114 us; speedup 1.0000x reference)
//
#include <hip/hip_runtime.h>
#include <hip/hip_bf16.h>

// EnhancedTelomeraseGNN on MI355X — dual-dtype-mode build.
// Round-2 produced NaN, consistent with inputs being f32 misread as bf16.
// This build detects the real device dtype at runtime (k_detect) and runs
// the matching path. All internal math fp32. a_e[e,h] = ea[e]*p[h] + q[h]
// algebraic collapse retained (kills both E x 64 x 256 edge GEMMs).
//
// Workspace (~82 MB worst case, f32 hmat): flag | pq[16] | cnt[N] | off[N+1]
// | csr_src[E] | csr_ea[E] | as[N,4] | ad[N,4] | hmat[N,256] (f32-sized) |
// nodeA f32[N,64] | nodeB f32[N,64] | g[64,64]

#define NN 50000
#define NE 400000
#define FIN 32
#define HIDC 64
#define NBATCH 64

typedef __hip_bfloat16 bf16;

__device__ __forceinline__ float b2f(bf16 v) { return __bfloat162float(v); }
__device__ __forceinline__ float cvt(bf16 v) { return __bfloat162float(v); }
__device__ __forceinline__ float cvt(float v) { return v; }
__device__ __forceinline__ float lrelu(float x) { return x > 0.f ? x : 0.2f * x; }
__device__ __forceinline__ float eluf(float x) { return x > 0.f ? x : (expf(x) - 1.f); }

struct AccB {
  static __device__ __forceinline__ float ld(const void* p, int i) {
    return b2f(((const bf16*)p)[i]);
  }
};
struct AccF {
  static __device__ __forceinline__ float ld(const void* p, int i) {
    return ((const float*)p)[i];
  }
};

// ---------------------------------------------------------------- dtype probe
// Even-indexed u16 words of x: real bf16 values of N(0,1) have exponent field
// in [96,159] essentially always; low-mantissa halves of f32 are uniform
// (~25% in range). Majority vote over 512 samples.
__global__ __launch_bounds__(64) void k_detect(const void* __restrict__ x,
                                               int* __restrict__ flag) {
  const unsigned short* u = (const unsigned short*)x;
  int t = threadIdx.x;
  int good = 0;
  for (int i = t; i < 512; i += 64) {
    unsigned short v = u[2 * i];
    int e = (v >> 7) & 0xFF;
    good += (e >= 96 && e <= 159) ? 1 : 0;
  }
  for (int o = 32; o; o >>= 1) good += __shfl_xor(good, o);
  if (t == 0) flag[0] = (good >= 384) ? 1 : 0;  // 1 = bf16 mode
}

// ---------------------------------------------------------------- p/q scalars
template <typename A>
__device__ __forceinline__ void pq_body(const void* We1, const void* atte1,
                                        const void* We2, const void* atte2,
                                        const void* edgeW, const void* edgeB,
                                        float* pq) {
  int t = threadIdx.x, h = t >> 6, c = t & 63;
  float sW1 = 0.f, sB1 = 0.f, sW2 = 0.f, sB2 = 0.f;
  for (int j = 0; j < HIDC; ++j) {
    float w = A::ld(edgeW, j), b = A::ld(edgeB, j);
    float we1 = A::ld(We1, j * 256 + h * 64 + c);
    float we2 = A::ld(We2, j * 256 + h * 64 + c);
    sW1 += w * we1; sB1 += b * we1;
    sW2 += w * we2; sB2 += b * we2;
  }
  float a1 = A::ld(atte1, h * 64 + c), a2 = A::ld(atte2, h * 64 + c);
  float p1 = sW1 * a1, q1 = sB1 * a1, p2 = sW2 * a2, q2 = sB2 * a2;
  for (int o = 32; o; o >>= 1) {
    p1 += __shfl_xor(p1, o); q1 += __shfl_xor(q1, o);
    p2 += __shfl_xor(p2, o); q2 += __shfl_xor(q2, o);
  }
  if (c == 0) { pq[h] = p1; pq[4 + h] = q1; pq[8 + h] = p2; pq[12 + h] = q2; }
}

__global__ __launch_bounds__(256) void k_pq(const int* __restrict__ flag,
    const void* We1, const void* atte1, const void* We2, const void* atte2,
    const void* edgeW, const void* edgeB, float* pq) {
  if (flag[0]) pq_body<AccB>(We1, atte1, We2, atte2, edgeW, edgeB, pq);
  else         pq_body<AccF>(We1, atte1, We2, atte2, edgeW, edgeB, pq);
}

// ---------------------------------------------------------------- node GEMM
// bf16 mode: W cached in LDS as bf16x2 pairs; hmat stored bf16.
template <int K, bool CONCAT>
__global__ __launch_bounds__(256) void k_gemm_bf(const int* __restrict__ flag,
    const bf16* __restrict__ x, const int* __restrict__ ntype,
    const bf16* __restrict__ emb, const float* __restrict__ Ain,
    const bf16* __restrict__ W, bf16* __restrict__ out) {
  if (!flag[0]) return;
  __shared__ __hip_bfloat162 Wl[(K / 2) * 256];
  __shared__ float Ar[4 * K];
  int t = threadIdx.x;
  for (int i = t; i < (K / 2) * 256; i += 256) {
    int k2 = i >> 8, j = i & 255;
    __hip_bfloat162 v;
    v.x = W[(2 * k2) * 256 + j];
    v.y = W[(2 * k2 + 1) * 256 + j];
    Wl[i] = v;
  }
  __syncthreads();
  for (int r0 = blockIdx.x * 4; r0 < NN; r0 += gridDim.x * 4) {
    for (int i = t; i < 4 * K; i += 256) {
      int r = i / K, k = i - r * K;
      int n = r0 + r;
      float v = 0.f;
      if (n < NN) {
        if constexpr (CONCAT)
          v = (k < FIN) ? b2f(x[(size_t)n * FIN + k])
                        : b2f(emb[ntype[n] * HIDC + (k - FIN)]);
        else
          v = Ain[(size_t)n * K + k];
      }
      Ar[i] = v;
    }
    __syncthreads();
    float a0 = 0.f, a1 = 0.f, a2 = 0.f, a3 = 0.f;
    for (int k2 = 0; k2 < K / 2; ++k2) {
      __hip_bfloat162 wv = Wl[k2 * 256 + t];
      float wx = b2f(wv.x), wy = b2f(wv.y);
      int k = 2 * k2;
      a0 += Ar[k] * wx + Ar[k + 1] * wy;
      a1 += Ar[K + k] * wx + Ar[K + k + 1] * wy;
      a2 += Ar[2 * K + k] * wx + Ar[2 * K + k + 1] * wy;
      a3 += Ar[3 * K + k] * wx + Ar[3 * K + k + 1] * wy;
    }
    size_t base = (size_t)r0 * 256;
    out[base + t]       = __float2bfloat16(a0);
    out[base + 256 + t] = __float2bfloat16(a1);
    out[base + 512 + t] = __float2bfloat16(a2);
    out[base + 768 + t] = __float2bfloat16(a3);
    __syncthreads();
  }
}

// f32 mode: W streamed from global (f32 W won't fit 64KB static LDS at K=96);
// hmat stored f32 for full precision.
template <int K, bool CONCAT>
__global__ __launch_bounds__(256) void k_gemm_f32(const int* __restrict__ flag,
    const float* __restrict__ x, const int* __restrict__ ntype,
    const float* __restrict__ emb, const float* __restrict__ Ain,
    const float* __restrict__ W, float* __restrict__ out) {
  if (flag[0]) return;
  __shared__ float Ar[4 * K];
  int t = threadIdx.x;
  for (int r0 = blockIdx.x * 4; r0 < NN; r0 += gridDim.x * 4) {
    for (int i = t; i < 4 * K; i += 256) {
      int r = i / K, k = i - r * K;
      int n = r0 + r;
      float v = 0.f;
      if (n < NN) {
        if constexpr (CONCAT)
          v = (k < FIN) ? x[(size_t)n * FIN + k]
                        : emb[ntype[n] * HIDC + (k - FIN)];
        else
          v = Ain[(size_t)n * K + k];
      }
      Ar[i] = v;
    }
    __syncthreads();
    float a0 = 0.f, a1 = 0.f, a2 = 0.f, a3 = 0.f;
    #pragma unroll 8
    for (int k = 0; k < K; ++k) {
      float w = W[k * 256 + t];
      a0 += Ar[k] * w;
      a1 += Ar[K + k] * w;
      a2 += Ar[2 * K + k] * w;
      a3 += Ar[3 * K + k] * w;
    }
    size_t base = (size_t)r0 * 256;
    out[base + t]       = a0;
    out[base + 256 + t] = a1;
    out[base + 512 + t] = a2;
    out[base + 768 + t] = a3;
    __syncthreads();
  }
}

// ---------------------------------------------------------------- per-node att
template <typename A, typename HT>
__device__ __forceinline__ void att_body(const HT* __restrict__ hmat,
    const void* atts, const void* attd, float* as_, float* ad_) {
  int wid = (blockIdx.x << 2) + (threadIdx.x >> 6);
  int lane = threadIdx.x & 63;
  if (wid >= NN) return;
  const HT* row = hmat + (size_t)wid * 256;
  for (int g = 0; g < 4; ++g) {
    float v = cvt(row[g * 64 + lane]);
    float sv = v * A::ld(atts, g * 64 + lane);
    float dv = v * A::ld(attd, g * 64 + lane);
    for (int o = 32; o; o >>= 1) { sv += __shfl_xor(sv, o); dv += __shfl_xor(dv, o); }
    if (lane == 0) { as_[wid * 4 + g] = sv; ad_[wid * 4 + g] = dv; }
  }
}

__global__ __launch_bounds__(256) void k_att(const int* __restrict__ flag,
    const void* hmat, const void* atts, const void* attd,
    float* as_, float* ad_) {
  if (flag[0]) att_body<AccB, bf16>((const bf16*)hmat, atts, attd, as_, ad_);
  else         att_body<AccF, float>((const float*)hmat, atts, attd, as_, ad_);
}

// ---------------------------------------------------------------- CSR build
__global__ void k_hist(const int* __restrict__ dst, int* __restrict__ cnt) {
  int e = blockIdx.x * 256 + threadIdx.x;
  if (e < NE) atomicAdd(&cnt[dst[e]], 1);
}

__global__ __launch_bounds__(1024) void k_scan(const int* __restrict__ cnt,
                                               int* __restrict__ off) {
  __shared__ int wsum[16];
  __shared__ int carry;
  int t = threadIdx.x, lane = t & 63, w = t >> 6;
  if (t == 0) { carry = 0; off[0] = 0; }
  __syncthreads();
  for (int base = 0; base < NN; base += 1024) {
    int idx = base + t;
    int v = (idx < NN) ? cnt[idx] : 0;
    int s = v;
    for (int o = 1; o < 64; o <<= 1) { int u = __shfl_up(s, o); if (lane >= o) s += u; }
    if (lane == 63) wsum[w] = s;
    __syncthreads();
    if (t < 16) {
      int ws = wsum[t];
      for (int o = 1; o < 16; o <<= 1) { int u = __shfl_up(ws, o); if (t >= o) ws += u; }
      wsum[t] = ws;
    }
    __syncthreads();
    int add = carry + (w ? wsum[w - 1] : 0);
    if (idx < NN) off[idx + 1] = add + s;
    __syncthreads();
    if (t == 0) carry += wsum[15];
    __syncthreads();
  }
}

template <typename A>
__device__ __forceinline__ void scatter_body(const int* src, const int* dst,
    const void* ea, const int* off, int* cur, int* csr_src, float* csr_ea) {
  int e = blockIdx.x * 256 + threadIdx.x;
  if (e >= NE) return;
  int d = dst[e];
  int slot = off[d] + atomicAdd(&cur[d], 1);
  csr_src[slot] = src[e];
  csr_ea[slot] = A::ld(ea, e);
}

__global__ void k_scatter(const int* __restrict__ flag, const int* src,
    const int* dst, const void* ea, const int* off, int* cur,
    int* csr_src, float* csr_ea) {
  if (flag[0]) scatter_body<AccB>(src, dst, ea, off, cur, csr_src, csr_ea);
  else         scatter_body<AccF>(src, dst, ea, off, cur, csr_src, csr_ea);
}

// ---------------------------------------------------------------- GAT agg
template <typename A, typename HT>
__device__ __forceinline__ void gat_body(const int* off, const int* csr_src,
    const float* csr_ea, const float* as_, const float* ad_,
    const HT* __restrict__ hmat, const float* pq, int pqo, const void* bias,
    float* out) {
  int wid = (blockIdx.x << 2) + (threadIdx.x >> 6);
  int lane = threadIdx.x & 63;
  if (wid >= NN) return;
  int beg = off[wid], end = off[wid + 1];
  float p0 = pq[pqo + 0], p1 = pq[pqo + 1], p2 = pq[pqo + 2], p3 = pq[pqo + 3];
  float q0 = pq[pqo + 4], q1 = pq[pqo + 5], q2 = pq[pqo + 6], q3 = pq[pqo + 7];
  float d0 = ad_[wid * 4 + 0], d1 = ad_[wid * 4 + 1];
  float d2 = ad_[wid * 4 + 2], d3 = ad_[wid * 4 + 3];
  float m0 = -INFINITY, m1 = -INFINITY, m2 = -INFINITY, m3 = -INFINITY;
  for (int e = beg + lane; e < end; e += 64) {
    int s = csr_src[e];
    float ea = csr_ea[e];
    const float4 a = *reinterpret_cast<const float4*>(&as_[s * 4]);
    m0 = fmaxf(m0, lrelu(a.x + d0 + ea * p0 + q0));
    m1 = fmaxf(m1, lrelu(a.y + d1 + ea * p1 + q1));
    m2 = fmaxf(m2, lrelu(a.z + d2 + ea * p2 + q2));
    m3 = fmaxf(m3, lrelu(a.w + d3 + ea * p3 + q3));
  }
  for (int o = 32; o; o >>= 1) {
    m0 = fmaxf(m0, __shfl_xor(m0, o));
    m1 = fmaxf(m1, __shfl_xor(m1, o));
    m2 = fmaxf(m2, __shfl_xor(m2, o));
    m3 = fmaxf(m3, __shfl_xor(m3, o));
  }
  float s0 = 0.f, s1 = 0.f, s2 = 0.f, s3 = 0.f;
  for (int e = beg + lane; e < end; e += 64) {
    int s = csr_src[e];
    float ea = csr_ea[e];
    const float4 a = *reinterpret_cast<const float4*>(&as_[s * 4]);
    s0 += expf(lrelu(a.x + d0 + ea * p0 + q0) - m0);
    s1 += expf(lrelu(a.y + d1 + ea * p1 + q1) - m1);
    s2 += expf(lrelu(a.z + d2 + ea * p2 + q2) - m2);
    s3 += expf(lrelu(a.w + d3 + ea * p3 + q3) - m3);
  }
  for (int o = 32; o; o >>= 1) {
    s0 += __shfl_xor(s0, o); s1 += __shfl_xor(s1, o);
    s2 += __shfl_xor(s2, o); s3 += __shfl_xor(s3, o);
  }
  float i0 = 1.f / (s0 + 1e-16f), i1 = 1.f / (s1 + 1e-16f);
  float i2 = 1.f / (s2 + 1e-16f), i3 = 1.f / (s3 + 1e-16f);
  float acc = 0.f;
  for (int e = beg; e < end; ++e) {
    int s = csr_src[e];
    float ea = csr_ea[e];
    const float4 a = *reinterpret_cast<const float4*>(&as_[s * 4]);
    float w0 = expf(lrelu(a.x + d0 + ea * p0 + q0) - m0) * i0;
    float w1 = expf(lrelu(a.y + d1 + ea * p1 + q1) - m1) * i1;
    float w2 = expf(lrelu(a.z + d2 + ea * p2 + q2) - m2) * i2;
    float w3 = expf(lrelu(a.w + d3 + ea * p3 + q3) - m3) * i3;
    const HT* hp = hmat + (size_t)s * 256;
    acc += w0 * cvt(hp[lane]) + w1 * cvt(hp[64 + lane]) +
           w2 * cvt(hp[128 + lane]) + w3 * cvt(hp[192 + lane]);
  }
  out[(size_t)wid * 64 + lane] = eluf(acc * 0.25f + A::ld(bias, lane));
}

__global__ __launch_bounds__(256) void k_gat(const int* __restrict__ flag,
    const int* off, const int* csr_src, const float* csr_ea, const float* as_,
    const float* ad_, const void* hmat, const float* pq, int pqo,
    const void* bias, float* out) {
  if (flag[0])
    gat_body<AccB, bf16>(off, csr_src, csr_ea, as_, ad_, (const bf16*)hmat,
                         pq, pqo, bias, out);
  else
    gat_body<AccF, float>(off, csr_src, csr_ea, as_, ad_, (const float*)hmat,
                          pq, pqo, bias, out);
}

// ---------------------------------------------------------------- SAGE fused
template <typename A>
__device__ __forceinline__ void sage_body(float* WlS, float* WrS,
    float (*aggS)[64], float (*rowS)[64], const int* off, const int* csr_src,
    const float* h3, const void* Wl, const void* Wr, const void* bias,
    float* out) {
  int t = threadIdx.x, lane = t & 63, w = t >> 6;
  for (int i = t; i < 4096; i += 256) { WlS[i] = A::ld(Wl, i); WrS[i] = A::ld(Wr, i); }
  __syncthreads();
  for (int n0 = blockIdx.x * 4; n0 < NN; n0 += gridDim.x * 4) {
    int wid = n0 + w;
    float aggv = 0.f, hv = 0.f;
    if (wid < NN) {
      int beg = off[wid], end = off[wid + 1];
      float acc = 0.f;
      for (int e = beg; e < end; ++e) acc += h3[(size_t)csr_src[e] * 64 + lane];
      aggv = acc / fmaxf((float)(end - beg), 1.f);
      hv = h3[(size_t)wid * 64 + lane];
    }
    aggS[w][lane] = aggv;
    rowS[w][lane] = hv;
    __syncthreads();
    if (wid < NN) {
      float sum = 0.f;
      for (int k = 0; k < 64; ++k)
        sum += aggS[w][k] * WlS[k * 64 + lane] + rowS[w][k] * WrS[k * 64 + lane];
      out[(size_t)wid * 64 + lane] = eluf(sum + A::ld(bias, lane));
    }
    __syncthreads();
  }
}

__global__ __launch_bounds__(256) void k_sage(const int* __restrict__ flag,
    const int* off, const int* csr_src, const float* h3, const void* Wl,
    const void* Wr, const void* bias, float* out) {
  __shared__ float WlS[4096];
  __shared__ float WrS[4096];
  __shared__ float aggS[4][64];
  __shared__ float rowS[4][64];
  if (flag[0])
    sage_body<AccB>(WlS, WrS, aggS, rowS, off, csr_src, h3, Wl, Wr, bias, out);
  else
    sage_body<AccF>(WlS, WrS, aggS, rowS, off, csr_src, h3, Wl, Wr, bias, out);
}

// ---------------------------------------------------------------- pooling
__device__ __forceinline__ int lowerb(const int* __restrict__ a, int n, int key) {
  int lo = 0, hi = n;
  while (lo < hi) { int mid = (lo + hi) >> 1; if (a[mid] < key) lo = mid + 1; else hi = mid; }
  return lo;
}

__global__ __launch_bounds__(256) void k_pool(const float* __restrict__ hs,
                                              const int* __restrict__ batch,
                                              float* __restrict__ g) {
  int b = blockIdx.x;
  int lo = lowerb(batch, NN, b), hi = lowerb(batch, NN, b + 1);
  int t = threadIdx.x, lane = t & 63, w = t >> 6;
  float acc = 0.f;
  for (int n = lo + w; n < hi; n += 4) acc += hs[(size_t)n * 64 + lane];
  __shared__ float red[4][64];
  red[w][lane] = acc;
  __syncthreads();
  if (w == 0) {
    float v = red[0][lane] + red[1][lane] + red[2][lane] + red[3][lane];
    g[b * 64 + lane] = v / fmaxf((float)(hi - lo), 1.f);
  }
}

// ---------------------------------------------------------------- MLP head
template <typename A>
__device__ __forceinline__ void head_body(float* gS, float* WS, float* hS,
    const float* g, const void* l1W, const void* l1b, const void* l2W,
    const void* l2b, const void* telW, const void* telb, const void* compW,
    const void* compb, const void* pchW, const void* pchb, void* out,
    int obf) {
  int t = threadIdx.x;
  for (int i = t; i < 4096; i += 256) { gS[i] = g[i]; WS[i] = A::ld(l1W, i); }
  __syncthreads();
  for (int i = t; i < 4096; i += 256) {
    int r = i >> 6, j = i & 63;
    float s = 0.f;
    for (int k = 0; k < 64; ++k) s += gS[r * 64 + k] * WS[k * 64 + j];
    hS[i] = eluf(s + A::ld(l1b, j));
  }
  __syncthreads();
  for (int i = t; i < 4096; i += 256) WS[i] = A::ld(l2W, i);
  __syncthreads();
  for (int i = t; i < 4096; i += 256) {
    int r = i >> 6, j = i & 63;
    float s = 0.f;
    for (int k = 0; k < 64; ++k) s += hS[r * 64 + k] * WS[k * 64 + j];
    gS[i] = s + A::ld(l2b, j);
  }
  __syncthreads();
  if (t < 192) {
    int head = t >> 6, r = t & 63;
    const void* Wv = head == 0 ? telW : (head == 1 ? compW : pchW);
    float bb = head == 0 ? A::ld(telb, 0)
                         : (head == 1 ? A::ld(compb, 0) : A::ld(pchb, 0));
    float s = 0.f;
    for (int k = 0; k < 64; ++k) s += gS[r * 64 + k] * A::ld(Wv, k);
    float val = s + bb;
    if (obf) ((bf16*)out)[t] = __float2bfloat16(val);
    else     ((float*)out)[t] = val;
  }
}

__global__ __launch_bounds__(256) void k_head(const int* __restrict__ flag,
    const float* g, const void* l1W, const void* l1b, const void* l2W,
    const void* l2b, const void* telW, const void* telb, const void* compW,
    const void* compb, const void* pchW, const void* pchb, void* out) {
  __shared__ float gS[4096];
  __shared__ float WS[4096];
  __shared__ float hS[4096];
  if (flag[0])
    head_body<AccB>(gS, WS, hS, g, l1W, l1b, l2W, l2b, telW, telb, compW,
                    compb, pchW, pchb, out, 1);
  else
    head_body<AccF>(gS, WS, hS, g, l1W, l1b, l2W, l2b, telW, telb, compW,
                    compb, pchW, pchb, out, 0);
}

// ---------------------------------------------------------------- launch
extern "C" void kernel_launch(void* const* d_in, const int* in_sizes, int n_in,
                              void* d_out, int out_size, void* d_ws, size_t ws_size,
                              hipStream_t stream) {
  const void* x     = d_in[0];
  const int*  eidx  = (const int*)d_in[1];
  const void* eattr = d_in[2];
  const int*  batch = (const int*)d_in[3];
  const int*  ntype = (const int*)d_in[4];
  const void* nemb  = d_in[5];
  const void* edgeW = d_in[6];
  const void* edgeB = d_in[7];
  const void* W1    = d_in[8];
  const void* atts1 = d_in[9];
  const void* attd1 = d_in[10];
  const void* We1   = d_in[11];
  const void* atte1 = d_in[12];
  const void* b1    = d_in[13];
  const void* W2    = d_in[14];
  const void* atts2 = d_in[15];
  const void* attd2 = d_in[16];
  const void* We2   = d_in[17];
  const void* atte2 = d_in[18];
  const void* b2    = d_in[19];
  const void* sageWl = d_in[20];
  const void* sageWr = d_in[21];
  const void* sageB  = d_in[22];
  const void* l1W = d_in[23];
  const void* l1b = d_in[24];
  const void* l2W = d_in[25];
  const void* l2b = d_in[26];
  const void* telW  = d_in[27];
  const void* telb  = d_in[28];
  const void* compW = d_in[29];
  const void* compb = d_in[30];
  const void* pchW  = d_in[31];
  const void* pchb  = d_in[32];

  char* wp = (char*)d_ws;
  auto alloc = [&](size_t bytes) -> char* {
    char* p = wp;
    wp += (bytes + 255) & ~(size_t)255;
    return p;
  };
  int*   flag    = (int*)alloc(4);
  float* pq      = (float*)alloc(16 * 4);
  int*   cnt     = (int*)alloc((size_t)NN * 4);
  int*   off     = (int*)alloc(((size_t)NN + 1) * 4);
  int*   csr_src = (int*)alloc((size_t)NE * 4);
  float* csr_ea  = (float*)alloc((size_t)NE * 4);
  float* as_     = (float*)alloc((size_t)NN * 16);
  float* ad_     = (float*)alloc((size_t)NN * 16);
  void*  hmat    = (void*)alloc((size_t)NN * 256 * 4);  // f32-sized worst case
  float* nodeA   = (float*)alloc((size_t)NN * 64 * 4);
  float* nodeB   = (float*)alloc((size_t)NN * 64 * 4);
  float* gbuf    = (float*)alloc(64 * 64 * 4);

  const int* srcI = eidx;
  const int* dstI = eidx + NE;

  k_detect<<<1, 64, 0, stream>>>(x, flag);
  hipMemsetAsync(cnt, 0, (size_t)NN * 4, stream);
  k_pq<<<1, 256, 0, stream>>>(flag, We1, atte1, We2, atte2, edgeW, edgeB, pq);
  k_hist<<<(NE + 255) / 256, 256, 0, stream>>>(dstI, cnt);
  k_scan<<<1, 1024, 0, stream>>>(cnt, off);
  hipMemsetAsync(cnt, 0, (size_t)NN * 4, stream);
  k_scatter<<<(NE + 255) / 256, 256, 0, stream>>>(flag, srcI, dstI, eattr, off,
                                                  cnt, csr_src, csr_ea);
  // GAT layer 1
  k_gemm_bf<96, true><<<512, 256, 0, stream>>>(flag, (const bf16*)x, ntype,
      (const bf16*)nemb, nullptr, (const bf16*)W1, (bf16*)hmat);
  k_gemm_f32<96, true><<<512, 256, 0, stream>>>(flag, (const float*)x, ntype,
      (const float*)nemb, nullptr, (const float*)W1, (float*)hmat);
  k_att<<<NN / 4, 256, 0, stream>>>(flag, hmat, atts1, attd1, as_, ad_);
  k_gat<<<NN / 4, 256, 0, stream>>>(flag, off, csr_src, csr_ea, as_, ad_, hmat,
                                    pq, 0, b1, nodeA);
  // GAT layer 2
  k_gemm_bf<64, false><<<512, 256, 0, stream>>>(flag, nullptr, nullptr, nullptr,
      nodeA, (const bf16*)W2, (bf16*)hmat);
  k_gemm_f32<64, false><<<512, 256, 0, stream>>>(flag, nullptr, nullptr, nullptr,
      nodeA, (const float*)W2, (float*)hmat);
  k_att<<<NN / 4, 256, 0, stream>>>(flag, hmat, atts2, attd2, as_, ad_);
  k_gat<<<NN / 4, 256, 0, stream>>>(flag, off, csr_src, csr_ea, as_, ad_, hmat,
                                    pq, 8, b2, nodeB);
  // SAGE + pool + head
  k_sage<<<1024, 256, 0, stream>>>(flag, off, csr_src, nodeB, sageWl, sageWr,
                                   sageB, nodeA);
  k_pool<<<NBATCH, 256, 0, stream>>>(nodeA, batch, gbuf);
  k_head<<<1, 256, 0, stream>>>(flag, gbuf, l1W, l1b, l2W, l2b, telW, telb,
                                compW, compb, pchW, pchb, d_out);
}

// Round 4
// 744.638 us; speedup vs baseline: 1.0718x; 1.0718x over previous
//
#include <hip/hip_runtime.h>
#include <hip/hip_bf16.h>

// EnhancedTelomeraseGNN on MI355X — round 4.
// Confirmed: inputs f32, output f32. Internal math f32; hmat stored bf16
// (messages only — attention scores computed from unrounded accumulators).
// a_e[e,h] = ea[e]*p[h] + q[h] algebraic collapse retained.
//
// Workspace (~63 MB): pq[16] | cnt[N] | off[N+1] | csr_src[E] | csr_ea[E] |
// csr_lg f32[E,4] | as[N,4] | ad[N,4] | hmat bf16[N,256] | nodeA f32[N,64] |
// nodeB f32[N,64] | g[64,64]

#define NN 50000
#define NE 400000
#define FIN 32
#define NBATCH 64

typedef __hip_bfloat16 bf16;

__device__ __forceinline__ float b2f(bf16 v) { return __bfloat162float(v); }
__device__ __forceinline__ float lrelu(float x) { return x > 0.f ? x : 0.2f * x; }
__device__ __forceinline__ float eluf(float x) { return x > 0.f ? x : (expf(x) - 1.f); }

// ---------------------------------------------------------------- p/q scalars
__global__ __launch_bounds__(256) void k_pq(
    const float* __restrict__ We1, const float* __restrict__ atte1,
    const float* __restrict__ We2, const float* __restrict__ atte2,
    const float* __restrict__ edgeW, const float* __restrict__ edgeB,
    float* __restrict__ pq) {
  int t = threadIdx.x, h = t >> 6, c = t & 63;
  float sW1 = 0.f, sB1 = 0.f, sW2 = 0.f, sB2 = 0.f;
  for (int j = 0; j < 64; ++j) {
    float w = edgeW[j], b = edgeB[j];
    float we1 = We1[j * 256 + h * 64 + c];
    float we2 = We2[j * 256 + h * 64 + c];
    sW1 += w * we1; sB1 += b * we1;
    sW2 += w * we2; sB2 += b * we2;
  }
  float a1 = atte1[h * 64 + c], a2 = atte2[h * 64 + c];
  float p1 = sW1 * a1, q1 = sB1 * a1, p2 = sW2 * a2, q2 = sB2 * a2;
  for (int o = 32; o; o >>= 1) {
    p1 += __shfl_xor(p1, o); q1 += __shfl_xor(q1, o);
    p2 += __shfl_xor(p2, o); q2 += __shfl_xor(q2, o);
  }
  if (c == 0) { pq[h] = p1; pq[4 + h] = q1; pq[8 + h] = p2; pq[12 + h] = q2; }
}

// ---------------------------------------------------------------- CSR build
__global__ void k_hist(const int* __restrict__ dst, int* __restrict__ cnt) {
  int e = blockIdx.x * 256 + threadIdx.x;
  if (e < NE) atomicAdd(&cnt[dst[e]], 1);
}

__global__ __launch_bounds__(1024) void k_scan(const int* __restrict__ cnt,
                                               int* __restrict__ off) {
  __shared__ int wsum[16];
  __shared__ int carry;
  int t = threadIdx.x, lane = t & 63, w = t >> 6;
  if (t == 0) { carry = 0; off[0] = 0; }
  __syncthreads();
  for (int base = 0; base < NN; base += 1024) {
    int idx = base + t;
    int v = (idx < NN) ? cnt[idx] : 0;
    int s = v;
    for (int o = 1; o < 64; o <<= 1) { int u = __shfl_up(s, o); if (lane >= o) s += u; }
    if (lane == 63) wsum[w] = s;
    __syncthreads();
    if (t < 16) {
      int ws = wsum[t];
      for (int o = 1; o < 16; o <<= 1) { int u = __shfl_up(ws, o); if (t >= o) ws += u; }
      wsum[t] = ws;
    }
    __syncthreads();
    int add = carry + (w ? wsum[w - 1] : 0);
    if (idx < NN) off[idx + 1] = add + s;
    __syncthreads();
    if (t == 0) carry += wsum[15];
    __syncthreads();
  }
}

__global__ void k_scatter(const int* __restrict__ src, const int* __restrict__ dst,
                          const float* __restrict__ ea, const int* __restrict__ off,
                          int* __restrict__ cur, int* __restrict__ csr_src,
                          float* __restrict__ csr_ea) {
  int e = blockIdx.x * 256 + threadIdx.x;
  if (e >= NE) return;
  int d = dst[e];
  int slot = off[d] + atomicAdd(&cur[d], 1);
  csr_src[slot] = src[e];
  csr_ea[slot] = ea[e];
}

// ---------------------------------------------------------------- GEMM + att
// out[n,0:256] = A[n,0:K] @ W[K,256]; hmat bf16; fused per-head att scores
// from unrounded f32 accumulators. Block handles one col-half (128 cols),
// W-half resident in LDS (K=96: 49KB). 8 rows per iteration.
// Thread t: col = t&127, rowgroup = t>>7 (4 rows each). Wave = 1 head x 4 rows.
template <int K, bool CONCAT>
__global__ __launch_bounds__(256) void k_gemm_att(
    const float* __restrict__ x, const int* __restrict__ ntype,
    const float* __restrict__ emb, const float* __restrict__ Ain,
    const float* __restrict__ W, const float* __restrict__ atts,
    const float* __restrict__ attd, bf16* __restrict__ hmat,
    float* __restrict__ as_, float* __restrict__ ad_) {
  __shared__ float Wl[K * 128];
  __shared__ float Ar[8 * K];
  int t = threadIdx.x;
  int lane = t & 63;
  int col = t & 127;
  int rg = t >> 7;          // 0/1: rows rg*4 .. rg*4+3
  int hih = (t >> 6) & 1;   // head within half
  int half = blockIdx.x & 1;  // gridDim.x must be even!
  for (int i = t; i < K * 128; i += 256)
    Wl[i] = W[(i >> 7) * 256 + half * 128 + (i & 127)];
  const int NU = (NN / 8) * 2;
  for (int u = blockIdx.x; u < NU; u += gridDim.x) {
    int r0 = (u >> 1) * 8;
    for (int i = t; i < 8 * K; i += 256) {
      int r = i / K, k = i - r * K;
      int n = r0 + r;
      float v;
      if constexpr (CONCAT)
        v = (k < FIN) ? x[n * FIN + k] : emb[ntype[n] * 64 + (k - FIN)];
      else
        v = Ain[(size_t)n * K + k];
      Ar[i] = v;
    }
    __syncthreads();
    const float* A0 = &Ar[(rg * 4 + 0) * K];
    const float* A1 = &Ar[(rg * 4 + 1) * K];
    const float* A2 = &Ar[(rg * 4 + 2) * K];
    const float* A3 = &Ar[(rg * 4 + 3) * K];
    float a0 = 0.f, a1 = 0.f, a2 = 0.f, a3 = 0.f;
    #pragma unroll 4
    for (int k = 0; k < K; k += 4) {
      float4 x0 = *reinterpret_cast<const float4*>(&A0[k]);
      float4 x1 = *reinterpret_cast<const float4*>(&A1[k]);
      float4 x2 = *reinterpret_cast<const float4*>(&A2[k]);
      float4 x3 = *reinterpret_cast<const float4*>(&A3[k]);
      float w0 = Wl[(k + 0) * 128 + col];
      float w1 = Wl[(k + 1) * 128 + col];
      float w2 = Wl[(k + 2) * 128 + col];
      float w3 = Wl[(k + 3) * 128 + col];
      a0 += x0.x * w0 + x0.y * w1 + x0.z * w2 + x0.w * w3;
      a1 += x1.x * w0 + x1.y * w1 + x1.z * w2 + x1.w * w3;
      a2 += x2.x * w0 + x2.y * w1 + x2.z * w2 + x2.w * w3;
      a3 += x3.x * w0 + x3.y * w1 + x3.z * w2 + x3.w * w3;
    }
    int gcol = half * 128 + col;
    size_t rb = (size_t)r0 + rg * 4;
    hmat[(rb + 0) * 256 + gcol] = __float2bfloat16(a0);
    hmat[(rb + 1) * 256 + gcol] = __float2bfloat16(a1);
    hmat[(rb + 2) * 256 + gcol] = __float2bfloat16(a2);
    hmat[(rb + 3) * 256 + gcol] = __float2bfloat16(a3);
    // fused attention scores (f32-exact, pre-rounding)
    float vs = atts[gcol], vd = attd[gcol];
    float s0 = a0 * vs, s1 = a1 * vs, s2 = a2 * vs, s3 = a3 * vs;
    float d0 = a0 * vd, d1 = a1 * vd, d2 = a2 * vd, d3 = a3 * vd;
    for (int o = 32; o; o >>= 1) {
      s0 += __shfl_xor(s0, o); s1 += __shfl_xor(s1, o);
      s2 += __shfl_xor(s2, o); s3 += __shfl_xor(s3, o);
      d0 += __shfl_xor(d0, o); d1 += __shfl_xor(d1, o);
      d2 += __shfl_xor(d2, o); d3 += __shfl_xor(d3, o);
    }
    if (lane == 0) {
      int h = half * 2 + hih;
      as_[(rb + 0) * 4 + h] = s0; as_[(rb + 1) * 4 + h] = s1;
      as_[(rb + 2) * 4 + h] = s2; as_[(rb + 3) * 4 + h] = s3;
      ad_[(rb + 0) * 4 + h] = d0; ad_[(rb + 1) * 4 + h] = d1;
      ad_[(rb + 2) * 4 + h] = d2; ad_[(rb + 3) * 4 + h] = d3;
    }
    __syncthreads();
  }
}

// ---------------------------------------------------------------- edge logits
// lg[e][h] = leaky_relu(as[src][h] + ad[dst][h] + ea*p[h] + q[h]), CSR order.
// Wave per dst node: ad_ broadcast once; as_ random 16B gathers (L2-resident).
__global__ __launch_bounds__(256) void k_elog(
    const int* __restrict__ off, const int* __restrict__ csr_src,
    const float* __restrict__ csr_ea, const float* __restrict__ as_,
    const float* __restrict__ ad_, const float* __restrict__ pq, int pqo,
    float4* __restrict__ lg) {
  int wid = (blockIdx.x << 2) + (threadIdx.x >> 6);
  int lane = threadIdx.x & 63;
  if (wid >= NN) return;
  float4 D = reinterpret_cast<const float4*>(ad_)[wid];
  float p0 = pq[pqo + 0], p1 = pq[pqo + 1], p2 = pq[pqo + 2], p3 = pq[pqo + 3];
  float q0 = pq[pqo + 4], q1 = pq[pqo + 5], q2 = pq[pqo + 6], q3 = pq[pqo + 7];
  int beg = off[wid], end = off[wid + 1];
  for (int e = beg + lane; e < end; e += 64) {
    int s = csr_src[e];
    float ea = csr_ea[e];
    float4 A = reinterpret_cast<const float4*>(as_)[s];
    lg[e] = make_float4(lrelu(A.x + D.x + ea * p0 + q0),
                        lrelu(A.y + D.y + ea * p1 + q1),
                        lrelu(A.z + D.z + ea * p2 + q2),
                        lrelu(A.w + D.w + ea * p3 + q3));
  }
}

// ---------------------------------------------------------------- GAT agg
// Wave per dst node. Pass A: online softmax (m,s) per head over coalesced
// logits. Pass B: weighted message accumulate (lane = channel), broadcast
// logit/src loads, bf16 hmat gathers.
__global__ __launch_bounds__(256) void k_gat(
    const int* __restrict__ off, const int* __restrict__ csr_src,
    const float4* __restrict__ lg, const bf16* __restrict__ hmat,
    const float* __restrict__ bias, float* __restrict__ out) {
  int wid = (blockIdx.x << 2) + (threadIdx.x >> 6);
  int lane = threadIdx.x & 63;
  if (wid >= NN) return;
  int beg = off[wid], end = off[wid + 1];
  float m0 = -INFINITY, m1 = -INFINITY, m2 = -INFINITY, m3 = -INFINITY;
  float s0 = 0.f, s1 = 0.f, s2 = 0.f, s3 = 0.f;
  for (int e = beg + lane; e < end; e += 64) {
    float4 l = lg[e];
    float nm;
    nm = fmaxf(m0, l.x); s0 = s0 * __expf(m0 - nm) + __expf(l.x - nm); m0 = nm;
    nm = fmaxf(m1, l.y); s1 = s1 * __expf(m1 - nm) + __expf(l.y - nm); m1 = nm;
    nm = fmaxf(m2, l.z); s2 = s2 * __expf(m2 - nm) + __expf(l.z - nm); m2 = nm;
    nm = fmaxf(m3, l.w); s3 = s3 * __expf(m3 - nm) + __expf(l.w - nm); m3 = nm;
  }
  // cross-lane combine; fmaxf(-80) guards NaN from (-inf) - (-inf)
  for (int o = 32; o; o >>= 1) {
    float om, os, nm;
    om = __shfl_xor(m0, o); os = __shfl_xor(s0, o); nm = fmaxf(m0, om);
    s0 = s0 * __expf(fmaxf(m0 - nm, -80.f)) + os * __expf(fmaxf(om - nm, -80.f)); m0 = nm;
    om = __shfl_xor(m1, o); os = __shfl_xor(s1, o); nm = fmaxf(m1, om);
    s1 = s1 * __expf(fmaxf(m1 - nm, -80.f)) + os * __expf(fmaxf(om - nm, -80.f)); m1 = nm;
    om = __shfl_xor(m2, o); os = __shfl_xor(s2, o); nm = fmaxf(m2, om);
    s2 = s2 * __expf(fmaxf(m2 - nm, -80.f)) + os * __expf(fmaxf(om - nm, -80.f)); m2 = nm;
    om = __shfl_xor(m3, o); os = __shfl_xor(s3, o); nm = fmaxf(m3, om);
    s3 = s3 * __expf(fmaxf(m3 - nm, -80.f)) + os * __expf(fmaxf(om - nm, -80.f)); m3 = nm;
  }
  float i0 = 1.f / (s0 + 1e-16f), i1 = 1.f / (s1 + 1e-16f);
  float i2 = 1.f / (s2 + 1e-16f), i3 = 1.f / (s3 + 1e-16f);
  float acc0 = 0.f, acc1 = 0.f, acc2 = 0.f, acc3 = 0.f;
  for (int e = beg; e < end; ++e) {
    float4 l = lg[e];                       // wave-uniform -> scalar load
    const bf16* hp = hmat + (size_t)csr_src[e] * 256;
    acc0 += __expf(l.x - m0) * b2f(hp[lane]);
    acc1 += __expf(l.y - m1) * b2f(hp[64 + lane]);
    acc2 += __expf(l.z - m2) * b2f(hp[128 + lane]);
    acc3 += __expf(l.w - m3) * b2f(hp[192 + lane]);
  }
  float r = 0.25f * (acc0 * i0 + acc1 * i1 + acc2 * i2 + acc3 * i3) + bias[lane];
  out[(size_t)wid * 64 + lane] = eluf(r);
}

// ---------------------------------------------------------------- SAGE fused
__global__ __launch_bounds__(256) void k_sage(
    const int* __restrict__ off, const int* __restrict__ csr_src,
    const float* __restrict__ h3, const float* __restrict__ Wl,
    const float* __restrict__ Wr, const float* __restrict__ bias,
    float* __restrict__ out) {
  __shared__ float WlS[4096];
  __shared__ float WrS[4096];
  __shared__ float aggS[4][64];
  __shared__ float rowS[4][64];
  int t = threadIdx.x, lane = t & 63, w = t >> 6;
  for (int i = t; i < 4096; i += 256) { WlS[i] = Wl[i]; WrS[i] = Wr[i]; }
  __syncthreads();
  for (int n0 = blockIdx.x * 4; n0 < NN; n0 += gridDim.x * 4) {
    int wid = n0 + w;
    float aggv = 0.f, hv = 0.f;
    if (wid < NN) {
      int beg = off[wid], end = off[wid + 1];
      float acc = 0.f;
      for (int e = beg; e < end; ++e) acc += h3[(size_t)csr_src[e] * 64 + lane];
      aggv = acc / fmaxf((float)(end - beg), 1.f);
      hv = h3[(size_t)wid * 64 + lane];
    }
    aggS[w][lane] = aggv;
    rowS[w][lane] = hv;
    __syncthreads();
    if (wid < NN) {
      float sum = 0.f;
      for (int k = 0; k < 64; ++k)
        sum += aggS[w][k] * WlS[k * 64 + lane] + rowS[w][k] * WrS[k * 64 + lane];
      out[(size_t)wid * 64 + lane] = eluf(sum + bias[lane]);
    }
    __syncthreads();
  }
}

// ---------------------------------------------------------------- pooling
__device__ __forceinline__ int lowerb(const int* __restrict__ a, int n, int key) {
  int lo = 0, hi = n;
  while (lo < hi) { int mid = (lo + hi) >> 1; if (a[mid] < key) lo = mid + 1; else hi = mid; }
  return lo;
}

__global__ __launch_bounds__(256) void k_pool(const float* __restrict__ hs,
                                              const int* __restrict__ batch,
                                              float* __restrict__ g) {
  int b = blockIdx.x;
  int lo = lowerb(batch, NN, b), hi = lowerb(batch, NN, b + 1);
  int t = threadIdx.x, lane = t & 63, w = t >> 6;
  float acc = 0.f;
  for (int n = lo + w; n < hi; n += 4) acc += hs[(size_t)n * 64 + lane];
  __shared__ float red[4][64];
  red[w][lane] = acc;
  __syncthreads();
  if (w == 0) {
    float v = red[0][lane] + red[1][lane] + red[2][lane] + red[3][lane];
    g[b * 64 + lane] = v / fmaxf((float)(hi - lo), 1.f);
  }
}

// ---------------------------------------------------------------- MLP head
__global__ __launch_bounds__(256) void k_head(
    const float* __restrict__ g, const float* __restrict__ l1W,
    const float* __restrict__ l1b, const float* __restrict__ l2W,
    const float* __restrict__ l2b, const float* __restrict__ telW,
    const float* __restrict__ telb, const float* __restrict__ compW,
    const float* __restrict__ compb, const float* __restrict__ pchW,
    const float* __restrict__ pchb, float* __restrict__ out) {
  __shared__ float gS[4096];
  __shared__ float WS[4096];
  __shared__ float hS[4096];
  int t = threadIdx.x;
  for (int i = t; i < 4096; i += 256) { gS[i] = g[i]; WS[i] = l1W[i]; }
  __syncthreads();
  for (int i = t; i < 4096; i += 256) {
    int r = i >> 6, j = i & 63;
    float s = 0.f;
    for (int k = 0; k < 64; ++k) s += gS[r * 64 + k] * WS[k * 64 + j];
    hS[i] = eluf(s + l1b[j]);
  }
  __syncthreads();
  for (int i = t; i < 4096; i += 256) WS[i] = l2W[i];
  __syncthreads();
  for (int i = t; i < 4096; i += 256) {
    int r = i >> 6, j = i & 63;
    float s = 0.f;
    for (int k = 0; k < 64; ++k) s += hS[r * 64 + k] * WS[k * 64 + j];
    gS[i] = s + l2b[j];
  }
  __syncthreads();
  if (t < 192) {
    int head = t >> 6, r = t & 63;
    const float* Wv = head == 0 ? telW : (head == 1 ? compW : pchW);
    float bb = head == 0 ? telb[0] : (head == 1 ? compb[0] : pchb[0]);
    float s = 0.f;
    for (int k = 0; k < 64; ++k) s += gS[r * 64 + k] * Wv[k];
    out[t] = s + bb;
  }
}

// ---------------------------------------------------------------- launch
extern "C" void kernel_launch(void* const* d_in, const int* in_sizes, int n_in,
                              void* d_out, int out_size, void* d_ws, size_t ws_size,
                              hipStream_t stream) {
  const float* x     = (const float*)d_in[0];
  const int*   eidx  = (const int*)d_in[1];
  const float* eattr = (const float*)d_in[2];
  const int*   batch = (const int*)d_in[3];
  const int*   ntype = (const int*)d_in[4];
  const float* nemb  = (const float*)d_in[5];
  const float* edgeW = (const float*)d_in[6];
  const float* edgeB = (const float*)d_in[7];
  const float* W1    = (const float*)d_in[8];
  const float* atts1 = (const float*)d_in[9];
  const float* attd1 = (const float*)d_in[10];
  const float* We1   = (const float*)d_in[11];
  const float* atte1 = (const float*)d_in[12];
  const float* b1    = (const float*)d_in[13];
  const float* W2    = (const float*)d_in[14];
  const float* atts2 = (const float*)d_in[15];
  const float* attd2 = (const float*)d_in[16];
  const float* We2   = (const float*)d_in[17];
  const float* atte2 = (const float*)d_in[18];
  const float* b2    = (const float*)d_in[19];
  const float* sageWl = (const float*)d_in[20];
  const float* sageWr = (const float*)d_in[21];
  const float* sageB  = (const float*)d_in[22];
  const float* l1W = (const float*)d_in[23];
  const float* l1b = (const float*)d_in[24];
  const float* l2W = (const float*)d_in[25];
  const float* l2b = (const float*)d_in[26];
  const float* telW  = (const float*)d_in[27];
  const float* telb  = (const float*)d_in[28];
  const float* compW = (const float*)d_in[29];
  const float* compb = (const float*)d_in[30];
  const float* pchW  = (const float*)d_in[31];
  const float* pchb  = (const float*)d_in[32];

  char* wp = (char*)d_ws;
  auto alloc = [&](size_t bytes) -> char* {
    char* p = wp;
    wp += (bytes + 255) & ~(size_t)255;
    return p;
  };
  float*  pq      = (float*)alloc(16 * 4);
  int*    cnt     = (int*)alloc((size_t)NN * 4);
  int*    off     = (int*)alloc(((size_t)NN + 1) * 4);
  int*    csr_src = (int*)alloc((size_t)NE * 4);
  float*  csr_ea  = (float*)alloc((size_t)NE * 4);
  float4* csr_lg  = (float4*)alloc((size_t)NE * 16);
  float*  as_     = (float*)alloc((size_t)NN * 16);
  float*  ad_     = (float*)alloc((size_t)NN * 16);
  bf16*   hmat    = (bf16*)alloc((size_t)NN * 256 * 2);
  float*  nodeA   = (float*)alloc((size_t)NN * 64 * 4);
  float*  nodeB   = (float*)alloc((size_t)NN * 64 * 4);
  float*  gbuf    = (float*)alloc(64 * 64 * 4);

  const int* srcI = eidx;
  const int* dstI = eidx + NE;

  hipMemsetAsync(cnt, 0, (size_t)NN * 4, stream);
  k_pq<<<1, 256, 0, stream>>>(We1, atte1, We2, atte2, edgeW, edgeB, pq);
  k_hist<<<(NE + 255) / 256, 256, 0, stream>>>(dstI, cnt);
  k_scan<<<1, 1024, 0, stream>>>(cnt, off);
  hipMemsetAsync(cnt, 0, (size_t)NN * 4, stream);
  k_scatter<<<(NE + 255) / 256, 256, 0, stream>>>(srcI, dstI, eattr, off, cnt,
                                                  csr_src, csr_ea);
  // GAT layer 1
  k_gemm_att<96, true><<<1024, 256, 0, stream>>>(
      x, ntype, nemb, nullptr, W1, atts1, attd1, hmat, as_, ad_);
  k_elog<<<NN / 4, 256, 0, stream>>>(off, csr_src, csr_ea, as_, ad_, pq, 0,
                                     csr_lg);
  k_gat<<<NN / 4, 256, 0, stream>>>(off, csr_src, csr_lg, hmat, b1, nodeA);
  // GAT layer 2
  k_gemm_att<64, false><<<1024, 256, 0, stream>>>(
      nullptr, nullptr, nullptr, nodeA, W2, atts2, attd2, hmat, as_, ad_);
  k_elog<<<NN / 4, 256, 0, stream>>>(off, csr_src, csr_ea, as_, ad_, pq, 8,
                                     csr_lg);
  k_gat<<<NN / 4, 256, 0, stream>>>(off, csr_src, csr_lg, hmat, b2, nodeB);
  // SAGE + pool + head
  k_sage<<<1024, 256, 0, stream>>>(off, csr_src, nodeB, sageWl, sageWr, sageB,
                                   nodeA);
  k_pool<<<NBATCH, 256, 0, stream>>>(nodeA, batch, gbuf);
  k_head<<<1, 256, 0, stream>>>(gbuf, l1W, l1b, l2W, l2b, telW, telb, compW,
                                compb, pchW, pchb, (float*)d_out);
}

// Round 5
// 659.839 us; speedup vs baseline: 1.2096x; 1.1285x over previous
//
#include <hip/hip_runtime.h>
#include <hip/hip_bf16.h>

// EnhancedTelomeraseGNN on MI355X — round 5.
// f32 inputs/outputs confirmed. Internal math f32; hmat bf16 (messages only;
// attention scores from unrounded f32 accumulators). a_e = ea*p[h] + q[h].
// Round-5 change: k_gemm_att rewritten with 4x4 register tiling
// (8 LDS b128 per 64 FMAs, was 8 LDS per 16 FMAs -> LDS-pipe-bound).
//
// Workspace (~63 MB): pq[16] | cnt[N] | off[N+1] | csr_src[E] | csr_ea[E] |
// csr_lg f32[E,4] | as[N,4] | ad[N,4] | hmat bf16[N,256] | nodeA f32[N,64] |
// nodeB f32[N,64] | g[64,64]

#define NN 50000
#define NE 400000
#define FIN 32
#define NBATCH 64

typedef __hip_bfloat16 bf16;

__device__ __forceinline__ float b2f(bf16 v) { return __bfloat162float(v); }
__device__ __forceinline__ float lrelu(float x) { return x > 0.f ? x : 0.2f * x; }
__device__ __forceinline__ float eluf(float x) { return x > 0.f ? x : (expf(x) - 1.f); }

__device__ __forceinline__ float4 f4fma(float s, float4 w, float4 c) {
  c.x = fmaf(s, w.x, c.x); c.y = fmaf(s, w.y, c.y);
  c.z = fmaf(s, w.z, c.z); c.w = fmaf(s, w.w, c.w);
  return c;
}

__device__ __forceinline__ unsigned short bfbits(float f) {
  bf16 b = __float2bfloat16(f);
  unsigned short u;
  __builtin_memcpy(&u, &b, 2);
  return u;
}

// ---------------------------------------------------------------- p/q scalars
__global__ __launch_bounds__(256) void k_pq(
    const float* __restrict__ We1, const float* __restrict__ atte1,
    const float* __restrict__ We2, const float* __restrict__ atte2,
    const float* __restrict__ edgeW, const float* __restrict__ edgeB,
    float* __restrict__ pq) {
  int t = threadIdx.x, h = t >> 6, c = t & 63;
  float sW1 = 0.f, sB1 = 0.f, sW2 = 0.f, sB2 = 0.f;
  for (int j = 0; j < 64; ++j) {
    float w = edgeW[j], b = edgeB[j];
    float we1 = We1[j * 256 + h * 64 + c];
    float we2 = We2[j * 256 + h * 64 + c];
    sW1 += w * we1; sB1 += b * we1;
    sW2 += w * we2; sB2 += b * we2;
  }
  float a1 = atte1[h * 64 + c], a2 = atte2[h * 64 + c];
  float p1 = sW1 * a1, q1 = sB1 * a1, p2 = sW2 * a2, q2 = sB2 * a2;
  for (int o = 32; o; o >>= 1) {
    p1 += __shfl_xor(p1, o); q1 += __shfl_xor(q1, o);
    p2 += __shfl_xor(p2, o); q2 += __shfl_xor(q2, o);
  }
  if (c == 0) { pq[h] = p1; pq[4 + h] = q1; pq[8 + h] = p2; pq[12 + h] = q2; }
}

// ---------------------------------------------------------------- CSR build
__global__ void k_hist(const int* __restrict__ dst, int* __restrict__ cnt) {
  int e = blockIdx.x * 256 + threadIdx.x;
  if (e < NE) atomicAdd(&cnt[dst[e]], 1);
}

__global__ __launch_bounds__(1024) void k_scan(const int* __restrict__ cnt,
                                               int* __restrict__ off) {
  __shared__ int wsum[16];
  __shared__ int carry;
  int t = threadIdx.x, lane = t & 63, w = t >> 6;
  if (t == 0) { carry = 0; off[0] = 0; }
  __syncthreads();
  for (int base = 0; base < NN; base += 1024) {
    int idx = base + t;
    int v = (idx < NN) ? cnt[idx] : 0;
    int s = v;
    for (int o = 1; o < 64; o <<= 1) { int u = __shfl_up(s, o); if (lane >= o) s += u; }
    if (lane == 63) wsum[w] = s;
    __syncthreads();
    if (t < 16) {
      int ws = wsum[t];
      for (int o = 1; o < 16; o <<= 1) { int u = __shfl_up(ws, o); if (t >= o) ws += u; }
      wsum[t] = ws;
    }
    __syncthreads();
    int add = carry + (w ? wsum[w - 1] : 0);
    if (idx < NN) off[idx + 1] = add + s;
    __syncthreads();
    if (t == 0) carry += wsum[15];
    __syncthreads();
  }
}

__global__ void k_scatter(const int* __restrict__ src, const int* __restrict__ dst,
                          const float* __restrict__ ea, const int* __restrict__ off,
                          int* __restrict__ cur, int* __restrict__ csr_src,
                          float* __restrict__ csr_ea) {
  int e = blockIdx.x * 256 + threadIdx.x;
  if (e >= NE) return;
  int d = dst[e];
  int slot = off[d] + atomicAdd(&cur[d], 1);
  csr_src[slot] = src[e];
  csr_ea[slot] = ea[e];
}

// ---------------------------------------------------------------- GEMM + att
// out[n,0:256] = A[n,0:K] @ W[K,256]; hmat bf16; fused att scores from f32
// accumulators. Block = one col-half (128 cols) x 32-row tiles.
// Thread: ct = t&31 -> cols ct*4..+3; rg = t>>5 -> rows rg*4..+3.
// Inner k-quad: 4x b128 W + 4x b128 A(broadcast) per 64 FMAs.
template <int K, bool CONCAT>
__global__ __launch_bounds__(256) void k_gemm_att(
    const float* __restrict__ x, const int* __restrict__ ntype,
    const float* __restrict__ emb, const float* __restrict__ Ain,
    const float* __restrict__ W, const float* __restrict__ atts,
    const float* __restrict__ attd, bf16* __restrict__ hmat,
    float* __restrict__ as_, float* __restrict__ ad_) {
  __shared__ float Wl[K * 128];   // [k][128 cols of this half]
  __shared__ float Ar[32 * K];    // [32 rows][K]
  int t = threadIdx.x;
  int ct = t & 31;
  int rg = t >> 5;
  int half = blockIdx.x & 1;      // gridDim.x must be even
  for (int i = t; i < K * 128; i += 256)
    Wl[i] = W[(i >> 7) * 256 + half * 128 + (i & 127)];
  int gcol = half * 128 + ct * 4;
  float4 vsv = *reinterpret_cast<const float4*>(&atts[gcol]);
  float4 vdv = *reinterpret_cast<const float4*>(&attd[gcol]);
  const int NT = (NN + 31) / 32;
  const int NU = NT * 2;
  for (int u = blockIdx.x; u < NU; u += gridDim.x) {
    int r0 = (u >> 1) * 32;
    for (int i = t; i < 32 * K; i += 256) {
      int r = i / K, k = i - r * K;
      int n = r0 + r;
      float v = 0.f;
      if (n < NN) {
        if constexpr (CONCAT)
          v = (k < FIN) ? x[n * FIN + k] : emb[ntype[n] * 64 + (k - FIN)];
        else
          v = Ain[(size_t)n * K + k];
      }
      Ar[i] = v;
    }
    __syncthreads();
    float4 c0 = {0.f, 0.f, 0.f, 0.f}, c1 = c0, c2 = c0, c3 = c0;
    const float* Arow = &Ar[rg * 4 * K];
    #pragma unroll 4
    for (int k = 0; k < K; k += 4) {
      float4 w0 = *reinterpret_cast<const float4*>(&Wl[(k + 0) * 128 + ct * 4]);
      float4 w1 = *reinterpret_cast<const float4*>(&Wl[(k + 1) * 128 + ct * 4]);
      float4 w2 = *reinterpret_cast<const float4*>(&Wl[(k + 2) * 128 + ct * 4]);
      float4 w3 = *reinterpret_cast<const float4*>(&Wl[(k + 3) * 128 + ct * 4]);
      float4 a0 = *reinterpret_cast<const float4*>(&Arow[0 * K + k]);
      float4 a1 = *reinterpret_cast<const float4*>(&Arow[1 * K + k]);
      float4 a2 = *reinterpret_cast<const float4*>(&Arow[2 * K + k]);
      float4 a3 = *reinterpret_cast<const float4*>(&Arow[3 * K + k]);
      c0 = f4fma(a0.x, w0, c0); c0 = f4fma(a0.y, w1, c0);
      c0 = f4fma(a0.z, w2, c0); c0 = f4fma(a0.w, w3, c0);
      c1 = f4fma(a1.x, w0, c1); c1 = f4fma(a1.y, w1, c1);
      c1 = f4fma(a1.z, w2, c1); c1 = f4fma(a1.w, w3, c1);
      c2 = f4fma(a2.x, w0, c2); c2 = f4fma(a2.y, w1, c2);
      c2 = f4fma(a2.z, w2, c2); c2 = f4fma(a2.w, w3, c2);
      c3 = f4fma(a3.x, w0, c3); c3 = f4fma(a3.y, w1, c3);
      c3 = f4fma(a3.z, w2, c3); c3 = f4fma(a3.w, w3, c3);
    }
    // epilogue: bf16 store (8B packed) + fused att-score partials
    int rb = r0 + rg * 4;
    float s0 = c0.x * vsv.x + c0.y * vsv.y + c0.z * vsv.z + c0.w * vsv.w;
    float s1 = c1.x * vsv.x + c1.y * vsv.y + c1.z * vsv.z + c1.w * vsv.w;
    float s2 = c2.x * vsv.x + c2.y * vsv.y + c2.z * vsv.z + c2.w * vsv.w;
    float s3 = c3.x * vsv.x + c3.y * vsv.y + c3.z * vsv.z + c3.w * vsv.w;
    float d0 = c0.x * vdv.x + c0.y * vdv.y + c0.z * vdv.z + c0.w * vdv.w;
    float d1 = c1.x * vdv.x + c1.y * vdv.y + c1.z * vdv.z + c1.w * vdv.w;
    float d2 = c2.x * vdv.x + c2.y * vdv.y + c2.z * vdv.z + c2.w * vdv.w;
    float d3 = c3.x * vdv.x + c3.y * vdv.y + c3.z * vdv.z + c3.w * vdv.w;
    ushort4 pk;
    if (rb + 0 < NN) {
      pk.x = bfbits(c0.x); pk.y = bfbits(c0.y); pk.z = bfbits(c0.z); pk.w = bfbits(c0.w);
      *reinterpret_cast<ushort4*>(&hmat[(size_t)(rb + 0) * 256 + gcol]) = pk;
    }
    if (rb + 1 < NN) {
      pk.x = bfbits(c1.x); pk.y = bfbits(c1.y); pk.z = bfbits(c1.z); pk.w = bfbits(c1.w);
      *reinterpret_cast<ushort4*>(&hmat[(size_t)(rb + 1) * 256 + gcol]) = pk;
    }
    if (rb + 2 < NN) {
      pk.x = bfbits(c2.x); pk.y = bfbits(c2.y); pk.z = bfbits(c2.z); pk.w = bfbits(c2.w);
      *reinterpret_cast<ushort4*>(&hmat[(size_t)(rb + 2) * 256 + gcol]) = pk;
    }
    if (rb + 3 < NN) {
      pk.x = bfbits(c3.x); pk.y = bfbits(c3.y); pk.z = bfbits(c3.z); pk.w = bfbits(c3.w);
      *reinterpret_cast<ushort4*>(&hmat[(size_t)(rb + 3) * 256 + gcol]) = pk;
    }
    // reduce score partials over the 16 col-threads of each head
    for (int o = 1; o < 16; o <<= 1) {
      s0 += __shfl_xor(s0, o); s1 += __shfl_xor(s1, o);
      s2 += __shfl_xor(s2, o); s3 += __shfl_xor(s3, o);
      d0 += __shfl_xor(d0, o); d1 += __shfl_xor(d1, o);
      d2 += __shfl_xor(d2, o); d3 += __shfl_xor(d3, o);
    }
    if ((t & 15) == 0) {
      int h = half * 2 + ((t >> 4) & 1);
      if (rb + 0 < NN) { as_[(rb + 0) * 4 + h] = s0; ad_[(rb + 0) * 4 + h] = d0; }
      if (rb + 1 < NN) { as_[(rb + 1) * 4 + h] = s1; ad_[(rb + 1) * 4 + h] = d1; }
      if (rb + 2 < NN) { as_[(rb + 2) * 4 + h] = s2; ad_[(rb + 2) * 4 + h] = d2; }
      if (rb + 3 < NN) { as_[(rb + 3) * 4 + h] = s3; ad_[(rb + 3) * 4 + h] = d3; }
    }
    __syncthreads();
  }
}

// ---------------------------------------------------------------- edge logits
__global__ __launch_bounds__(256) void k_elog(
    const int* __restrict__ off, const int* __restrict__ csr_src,
    const float* __restrict__ csr_ea, const float* __restrict__ as_,
    const float* __restrict__ ad_, const float* __restrict__ pq, int pqo,
    float4* __restrict__ lg) {
  int wid = (blockIdx.x << 2) + (threadIdx.x >> 6);
  int lane = threadIdx.x & 63;
  if (wid >= NN) return;
  float4 D = reinterpret_cast<const float4*>(ad_)[wid];
  float p0 = pq[pqo + 0], p1 = pq[pqo + 1], p2 = pq[pqo + 2], p3 = pq[pqo + 3];
  float q0 = pq[pqo + 4], q1 = pq[pqo + 5], q2 = pq[pqo + 6], q3 = pq[pqo + 7];
  int beg = off[wid], end = off[wid + 1];
  for (int e = beg + lane; e < end; e += 64) {
    int s = csr_src[e];
    float ea = csr_ea[e];
    float4 A = reinterpret_cast<const float4*>(as_)[s];
    lg[e] = make_float4(lrelu(A.x + D.x + ea * p0 + q0),
                        lrelu(A.y + D.y + ea * p1 + q1),
                        lrelu(A.z + D.z + ea * p2 + q2),
                        lrelu(A.w + D.w + ea * p3 + q3));
  }
}

// ---------------------------------------------------------------- GAT agg
__global__ __launch_bounds__(256) void k_gat(
    const int* __restrict__ off, const int* __restrict__ csr_src,
    const float4* __restrict__ lg, const bf16* __restrict__ hmat,
    const float* __restrict__ bias, float* __restrict__ out) {
  int wid = (blockIdx.x << 2) + (threadIdx.x >> 6);
  int lane = threadIdx.x & 63;
  if (wid >= NN) return;
  int beg = off[wid], end = off[wid + 1];
  float m0 = -INFINITY, m1 = -INFINITY, m2 = -INFINITY, m3 = -INFINITY;
  float s0 = 0.f, s1 = 0.f, s2 = 0.f, s3 = 0.f;
  for (int e = beg + lane; e < end; e += 64) {
    float4 l = lg[e];
    float nm;
    nm = fmaxf(m0, l.x); s0 = s0 * __expf(m0 - nm) + __expf(l.x - nm); m0 = nm;
    nm = fmaxf(m1, l.y); s1 = s1 * __expf(m1 - nm) + __expf(l.y - nm); m1 = nm;
    nm = fmaxf(m2, l.z); s2 = s2 * __expf(m2 - nm) + __expf(l.z - nm); m2 = nm;
    nm = fmaxf(m3, l.w); s3 = s3 * __expf(m3 - nm) + __expf(l.w - nm); m3 = nm;
  }
  for (int o = 32; o; o >>= 1) {
    float om, os, nm;
    om = __shfl_xor(m0, o); os = __shfl_xor(s0, o); nm = fmaxf(m0, om);
    s0 = s0 * __expf(fmaxf(m0 - nm, -80.f)) + os * __expf(fmaxf(om - nm, -80.f)); m0 = nm;
    om = __shfl_xor(m1, o); os = __shfl_xor(s1, o); nm = fmaxf(m1, om);
    s1 = s1 * __expf(fmaxf(m1 - nm, -80.f)) + os * __expf(fmaxf(om - nm, -80.f)); m1 = nm;
    om = __shfl_xor(m2, o); os = __shfl_xor(s2, o); nm = fmaxf(m2, om);
    s2 = s2 * __expf(fmaxf(m2 - nm, -80.f)) + os * __expf(fmaxf(om - nm, -80.f)); m2 = nm;
    om = __shfl_xor(m3, o); os = __shfl_xor(s3, o); nm = fmaxf(m3, om);
    s3 = s3 * __expf(fmaxf(m3 - nm, -80.f)) + os * __expf(fmaxf(om - nm, -80.f)); m3 = nm;
  }
  float i0 = 1.f / (s0 + 1e-16f), i1 = 1.f / (s1 + 1e-16f);
  float i2 = 1.f / (s2 + 1e-16f), i3 = 1.f / (s3 + 1e-16f);
  float acc0 = 0.f, acc1 = 0.f, acc2 = 0.f, acc3 = 0.f;
  for (int e = beg; e < end; ++e) {
    float4 l = lg[e];
    const bf16* hp = hmat + (size_t)csr_src[e] * 256;
    acc0 += __expf(l.x - m0) * b2f(hp[lane]);
    acc1 += __expf(l.y - m1) * b2f(hp[64 + lane]);
    acc2 += __expf(l.z - m2) * b2f(hp[128 + lane]);
    acc3 += __expf(l.w - m3) * b2f(hp[192 + lane]);
  }
  float r = 0.25f * (acc0 * i0 + acc1 * i1 + acc2 * i2 + acc3 * i3) + bias[lane];
  out[(size_t)wid * 64 + lane] = eluf(r);
}

// ---------------------------------------------------------------- SAGE fused
__global__ __launch_bounds__(256) void k_sage(
    const int* __restrict__ off, const int* __restrict__ csr_src,
    const float* __restrict__ h3, const float* __restrict__ Wl,
    const float* __restrict__ Wr, const float* __restrict__ bias,
    float* __restrict__ out) {
  __shared__ float WlS[4096];
  __shared__ float WrS[4096];
  __shared__ float aggS[4][64];
  __shared__ float rowS[4][64];
  int t = threadIdx.x, lane = t & 63, w = t >> 6;
  for (int i = t; i < 4096; i += 256) { WlS[i] = Wl[i]; WrS[i] = Wr[i]; }
  __syncthreads();
  for (int n0 = blockIdx.x * 4; n0 < NN; n0 += gridDim.x * 4) {
    int wid = n0 + w;
    float aggv = 0.f, hv = 0.f;
    if (wid < NN) {
      int beg = off[wid], end = off[wid + 1];
      float acc = 0.f;
      for (int e = beg; e < end; ++e) acc += h3[(size_t)csr_src[e] * 64 + lane];
      aggv = acc / fmaxf((float)(end - beg), 1.f);
      hv = h3[(size_t)wid * 64 + lane];
    }
    aggS[w][lane] = aggv;
    rowS[w][lane] = hv;
    __syncthreads();
    if (wid < NN) {
      float sum = 0.f;
      for (int k = 0; k < 64; ++k)
        sum += aggS[w][k] * WlS[k * 64 + lane] + rowS[w][k] * WrS[k * 64 + lane];
      out[(size_t)wid * 64 + lane] = eluf(sum + bias[lane]);
    }
    __syncthreads();
  }
}

// ---------------------------------------------------------------- pooling
__device__ __forceinline__ int lowerb(const int* __restrict__ a, int n, int key) {
  int lo = 0, hi = n;
  while (lo < hi) { int mid = (lo + hi) >> 1; if (a[mid] < key) lo = mid + 1; else hi = mid; }
  return lo;
}

__global__ __launch_bounds__(256) void k_pool(const float* __restrict__ hs,
                                              const int* __restrict__ batch,
                                              float* __restrict__ g) {
  int b = blockIdx.x;
  int lo = lowerb(batch, NN, b), hi = lowerb(batch, NN, b + 1);
  int t = threadIdx.x, lane = t & 63, w = t >> 6;
  float acc = 0.f;
  for (int n = lo + w; n < hi; n += 4) acc += hs[(size_t)n * 64 + lane];
  __shared__ float red[4][64];
  red[w][lane] = acc;
  __syncthreads();
  if (w == 0) {
    float v = red[0][lane] + red[1][lane] + red[2][lane] + red[3][lane];
    g[b * 64 + lane] = v / fmaxf((float)(hi - lo), 1.f);
  }
}

// ---------------------------------------------------------------- MLP head
__global__ __launch_bounds__(256) void k_head(
    const float* __restrict__ g, const float* __restrict__ l1W,
    const float* __restrict__ l1b, const float* __restrict__ l2W,
    const float* __restrict__ l2b, const float* __restrict__ telW,
    const float* __restrict__ telb, const float* __restrict__ compW,
    const float* __restrict__ compb, const float* __restrict__ pchW,
    const float* __restrict__ pchb, float* __restrict__ out) {
  __shared__ float gS[4096];
  __shared__ float WS[4096];
  __shared__ float hS[4096];
  int t = threadIdx.x;
  for (int i = t; i < 4096; i += 256) { gS[i] = g[i]; WS[i] = l1W[i]; }
  __syncthreads();
  for (int i = t; i < 4096; i += 256) {
    int r = i >> 6, j = i & 63;
    float s = 0.f;
    for (int k = 0; k < 64; ++k) s += gS[r * 64 + k] * WS[k * 64 + j];
    hS[i] = eluf(s + l1b[j]);
  }
  __syncthreads();
  for (int i = t; i < 4096; i += 256) WS[i] = l2W[i];
  __syncthreads();
  for (int i = t; i < 4096; i += 256) {
    int r = i >> 6, j = i & 63;
    float s = 0.f;
    for (int k = 0; k < 64; ++k) s += hS[r * 64 + k] * WS[k * 64 + j];
    gS[i] = s + l2b[j];
  }
  __syncthreads();
  if (t < 192) {
    int head = t >> 6, r = t & 63;
    const float* Wv = head == 0 ? telW : (head == 1 ? compW : pchW);
    float bb = head == 0 ? telb[0] : (head == 1 ? compb[0] : pchb[0]);
    float s = 0.f;
    for (int k = 0; k < 64; ++k) s += gS[r * 64 + k] * Wv[k];
    out[t] = s + bb;
  }
}

// ---------------------------------------------------------------- launch
extern "C" void kernel_launch(void* const* d_in, const int* in_sizes, int n_in,
                              void* d_out, int out_size, void* d_ws, size_t ws_size,
                              hipStream_t stream) {
  const float* x     = (const float*)d_in[0];
  const int*   eidx  = (const int*)d_in[1];
  const float* eattr = (const float*)d_in[2];
  const int*   batch = (const int*)d_in[3];
  const int*   ntype = (const int*)d_in[4];
  const float* nemb  = (const float*)d_in[5];
  const float* edgeW = (const float*)d_in[6];
  const float* edgeB = (const float*)d_in[7];
  const float* W1    = (const float*)d_in[8];
  const float* atts1 = (const float*)d_in[9];
  const float* attd1 = (const float*)d_in[10];
  const float* We1   = (const float*)d_in[11];
  const float* atte1 = (const float*)d_in[12];
  const float* b1    = (const float*)d_in[13];
  const float* W2    = (const float*)d_in[14];
  const float* atts2 = (const float*)d_in[15];
  const float* attd2 = (const float*)d_in[16];
  const float* We2   = (const float*)d_in[17];
  const float* atte2 = (const float*)d_in[18];
  const float* b2    = (const float*)d_in[19];
  const float* sageWl = (const float*)d_in[20];
  const float* sageWr = (const float*)d_in[21];
  const float* sageB  = (const float*)d_in[22];
  const float* l1W = (const float*)d_in[23];
  const float* l1b = (const float*)d_in[24];
  const float* l2W = (const float*)d_in[25];
  const float* l2b = (const float*)d_in[26];
  const float* telW  = (const float*)d_in[27];
  const float* telb  = (const float*)d_in[28];
  const float* compW = (const float*)d_in[29];
  const float* compb = (const float*)d_in[30];
  const float* pchW  = (const float*)d_in[31];
  const float* pchb  = (const float*)d_in[32];

  char* wp = (char*)d_ws;
  auto alloc = [&](size_t bytes) -> char* {
    char* p = wp;
    wp += (bytes + 255) & ~(size_t)255;
    return p;
  };
  float*  pq      = (float*)alloc(16 * 4);
  int*    cnt     = (int*)alloc((size_t)NN * 4);
  int*    off     = (int*)alloc(((size_t)NN + 1) * 4);
  int*    csr_src = (int*)alloc((size_t)NE * 4);
  float*  csr_ea  = (float*)alloc((size_t)NE * 4);
  float4* csr_lg  = (float4*)alloc((size_t)NE * 16);
  float*  as_     = (float*)alloc((size_t)NN * 16);
  float*  ad_     = (float*)alloc((size_t)NN * 16);
  bf16*   hmat    = (bf16*)alloc((size_t)NN * 256 * 2);
  float*  nodeA   = (float*)alloc((size_t)NN * 64 * 4);
  float*  nodeB   = (float*)alloc((size_t)NN * 64 * 4);
  float*  gbuf    = (float*)alloc(64 * 64 * 4);

  const int* srcI = eidx;
  const int* dstI = eidx + NE;

  hipMemsetAsync(cnt, 0, (size_t)NN * 4, stream);
  k_pq<<<1, 256, 0, stream>>>(We1, atte1, We2, atte2, edgeW, edgeB, pq);
  k_hist<<<(NE + 255) / 256, 256, 0, stream>>>(dstI, cnt);
  k_scan<<<1, 1024, 0, stream>>>(cnt, off);
  hipMemsetAsync(cnt, 0, (size_t)NN * 4, stream);
  k_scatter<<<(NE + 255) / 256, 256, 0, stream>>>(srcI, dstI, eattr, off, cnt,
                                                  csr_src, csr_ea);
  // GAT layer 1
  k_gemm_att<96, true><<<1024, 256, 0, stream>>>(
      x, ntype, nemb, nullptr, W1, atts1, attd1, hmat, as_, ad_);
  k_elog<<<NN / 4, 256, 0, stream>>>(off, csr_src, csr_ea, as_, ad_, pq, 0,
                                     csr_lg);
  k_gat<<<NN / 4, 256, 0, stream>>>(off, csr_src, csr_lg, hmat, b1, nodeA);
  // GAT layer 2
  k_gemm_att<64, false><<<1024, 256, 0, stream>>>(
      nullptr, nullptr, nullptr, nodeA, W2, atts2, attd2, hmat, as_, ad_);
  k_elog<<<NN / 4, 256, 0, stream>>>(off, csr_src, csr_ea, as_, ad_, pq, 8,
                                     csr_lg);
  k_gat<<<NN / 4, 256, 0, stream>>>(off, csr_src, csr_lg, hmat, b2, nodeB);
  // SAGE + pool + head
  k_sage<<<1024, 256, 0, stream>>>(off, csr_src, nodeB, sageWl, sageWr, sageB,
                                   nodeA);
  k_pool<<<NBATCH, 256, 0, stream>>>(nodeA, batch, gbuf);
  k_head<<<1, 256, 0, stream>>>(gbuf, l1W, l1b, l2W, l2b, telW, telb, compW,
                                compb, pchW, pchb, (float*)d_out);
}

// Round 6
// 543.661 us; speedup vs baseline: 1.4680x; 1.2137x over previous
//
#include <hip/hip_runtime.h>
#include <hip/hip_bf16.h>

// EnhancedTelomeraseGNN on MI355X — round 6.
// f32 in/out. Internal math f32; hmat bf16 (messages only). a_e = ea*p+q.
// Round-6: (1) k_sage split into k_agg (pure gather, no barriers) +
// k_sage_mm (register-tiled dual GEMM). (2) k_elog deleted — logits computed
// in-register in k_gat (lane = edge, deg<=64 fast path; slow fallback else).
// (3) k_gat pass B: one uint2 (4 flat channels) per lane per edge + ds_read
// weight; head-mean via shfl_xor(16,32).
//
// Workspace (~70 MB): pq | cnt | off | csr_src | csr_ea | as | ad |
// hmat bf16[N,256] | nodeA f32[N,64] | nodeB f32[N,64] | agg f32[N,64] | g

#define NN 50000
#define NE 400000
#define FIN 32
#define NBATCH 64

typedef __hip_bfloat16 bf16;

__device__ __forceinline__ float b2f(bf16 v) { return __bfloat162float(v); }
__device__ __forceinline__ float lrelu(float x) { return x > 0.f ? x : 0.2f * x; }
__device__ __forceinline__ float eluf(float x) { return x > 0.f ? x : (expf(x) - 1.f); }

__device__ __forceinline__ float4 f4fma(float s, float4 w, float4 c) {
  c.x = fmaf(s, w.x, c.x); c.y = fmaf(s, w.y, c.y);
  c.z = fmaf(s, w.z, c.z); c.w = fmaf(s, w.w, c.w);
  return c;
}

// unpack 4 consecutive bf16 (little-endian in uint2) to float4 — exact
__device__ __forceinline__ float4 upk4(uint2 u) {
  float4 f;
  f.x = __uint_as_float(u.x << 16);
  f.y = __uint_as_float(u.x & 0xffff0000u);
  f.z = __uint_as_float(u.y << 16);
  f.w = __uint_as_float(u.y & 0xffff0000u);
  return f;
}

__device__ __forceinline__ unsigned short bfbits(float f) {
  bf16 b = __float2bfloat16(f);
  unsigned short u;
  __builtin_memcpy(&u, &b, 2);
  return u;
}

// ---------------------------------------------------------------- p/q scalars
__global__ __launch_bounds__(256) void k_pq(
    const float* __restrict__ We1, const float* __restrict__ atte1,
    const float* __restrict__ We2, const float* __restrict__ atte2,
    const float* __restrict__ edgeW, const float* __restrict__ edgeB,
    float* __restrict__ pq) {
  int t = threadIdx.x, h = t >> 6, c = t & 63;
  float sW1 = 0.f, sB1 = 0.f, sW2 = 0.f, sB2 = 0.f;
  for (int j = 0; j < 64; ++j) {
    float w = edgeW[j], b = edgeB[j];
    float we1 = We1[j * 256 + h * 64 + c];
    float we2 = We2[j * 256 + h * 64 + c];
    sW1 += w * we1; sB1 += b * we1;
    sW2 += w * we2; sB2 += b * we2;
  }
  float a1 = atte1[h * 64 + c], a2 = atte2[h * 64 + c];
  float p1 = sW1 * a1, q1 = sB1 * a1, p2 = sW2 * a2, q2 = sB2 * a2;
  for (int o = 32; o; o >>= 1) {
    p1 += __shfl_xor(p1, o); q1 += __shfl_xor(q1, o);
    p2 += __shfl_xor(p2, o); q2 += __shfl_xor(q2, o);
  }
  if (c == 0) { pq[h] = p1; pq[4 + h] = q1; pq[8 + h] = p2; pq[12 + h] = q2; }
}

// ---------------------------------------------------------------- CSR build
__global__ void k_hist(const int* __restrict__ dst, int* __restrict__ cnt) {
  int e = blockIdx.x * 256 + threadIdx.x;
  if (e < NE) atomicAdd(&cnt[dst[e]], 1);
}

__global__ __launch_bounds__(1024) void k_scan(const int* __restrict__ cnt,
                                               int* __restrict__ off) {
  __shared__ int wsum[16];
  __shared__ int carry;
  int t = threadIdx.x, lane = t & 63, w = t >> 6;
  if (t == 0) { carry = 0; off[0] = 0; }
  __syncthreads();
  for (int base = 0; base < NN; base += 1024) {
    int idx = base + t;
    int v = (idx < NN) ? cnt[idx] : 0;
    int s = v;
    for (int o = 1; o < 64; o <<= 1) { int u = __shfl_up(s, o); if (lane >= o) s += u; }
    if (lane == 63) wsum[w] = s;
    __syncthreads();
    if (t < 16) {
      int ws = wsum[t];
      for (int o = 1; o < 16; o <<= 1) { int u = __shfl_up(ws, o); if (t >= o) ws += u; }
      wsum[t] = ws;
    }
    __syncthreads();
    int add = carry + (w ? wsum[w - 1] : 0);
    if (idx < NN) off[idx + 1] = add + s;
    __syncthreads();
    if (t == 0) carry += wsum[15];
    __syncthreads();
  }
}

__global__ void k_scatter(const int* __restrict__ src, const int* __restrict__ dst,
                          const float* __restrict__ ea, const int* __restrict__ off,
                          int* __restrict__ cur, int* __restrict__ csr_src,
                          float* __restrict__ csr_ea) {
  int e = blockIdx.x * 256 + threadIdx.x;
  if (e >= NE) return;
  int d = dst[e];
  int slot = off[d] + atomicAdd(&cur[d], 1);
  csr_src[slot] = src[e];
  csr_ea[slot] = ea[e];
}

// ---------------------------------------------------------------- GEMM + att
// out[n,0:256] = A[n,0:K] @ W[K,256]; hmat bf16; fused att scores from f32
// accumulators. Block = one col-half (128 cols) x 32-row tiles; thread 4x4.
template <int K, bool CONCAT>
__global__ __launch_bounds__(256) void k_gemm_att(
    const float* __restrict__ x, const int* __restrict__ ntype,
    const float* __restrict__ emb, const float* __restrict__ Ain,
    const float* __restrict__ W, const float* __restrict__ atts,
    const float* __restrict__ attd, bf16* __restrict__ hmat,
    float* __restrict__ as_, float* __restrict__ ad_) {
  __shared__ float Wl[K * 128];
  __shared__ float Ar[32 * K];
  int t = threadIdx.x;
  int ct = t & 31;
  int rg = t >> 5;
  int half = blockIdx.x & 1;      // gridDim.x must be even
  for (int i = t; i < K * 128; i += 256)
    Wl[i] = W[(i >> 7) * 256 + half * 128 + (i & 127)];
  int gcol = half * 128 + ct * 4;
  float4 vsv = *reinterpret_cast<const float4*>(&atts[gcol]);
  float4 vdv = *reinterpret_cast<const float4*>(&attd[gcol]);
  const int NT = (NN + 31) / 32;
  const int NU = NT * 2;
  for (int u = blockIdx.x; u < NU; u += gridDim.x) {
    int r0 = (u >> 1) * 32;
    for (int i = t; i < 32 * K; i += 256) {
      int r = i / K, k = i - r * K;
      int n = r0 + r;
      float v = 0.f;
      if (n < NN) {
        if constexpr (CONCAT)
          v = (k < FIN) ? x[n * FIN + k] : emb[ntype[n] * 64 + (k - FIN)];
        else
          v = Ain[(size_t)n * K + k];
      }
      Ar[i] = v;
    }
    __syncthreads();
    float4 c0 = {0.f, 0.f, 0.f, 0.f}, c1 = c0, c2 = c0, c3 = c0;
    const float* Arow = &Ar[rg * 4 * K];
    #pragma unroll 4
    for (int k = 0; k < K; k += 4) {
      float4 w0 = *reinterpret_cast<const float4*>(&Wl[(k + 0) * 128 + ct * 4]);
      float4 w1 = *reinterpret_cast<const float4*>(&Wl[(k + 1) * 128 + ct * 4]);
      float4 w2 = *reinterpret_cast<const float4*>(&Wl[(k + 2) * 128 + ct * 4]);
      float4 w3 = *reinterpret_cast<const float4*>(&Wl[(k + 3) * 128 + ct * 4]);
      float4 a0 = *reinterpret_cast<const float4*>(&Arow[0 * K + k]);
      float4 a1 = *reinterpret_cast<const float4*>(&Arow[1 * K + k]);
      float4 a2 = *reinterpret_cast<const float4*>(&Arow[2 * K + k]);
      float4 a3 = *reinterpret_cast<const float4*>(&Arow[3 * K + k]);
      c0 = f4fma(a0.x, w0, c0); c0 = f4fma(a0.y, w1, c0);
      c0 = f4fma(a0.z, w2, c0); c0 = f4fma(a0.w, w3, c0);
      c1 = f4fma(a1.x, w0, c1); c1 = f4fma(a1.y, w1, c1);
      c1 = f4fma(a1.z, w2, c1); c1 = f4fma(a1.w, w3, c1);
      c2 = f4fma(a2.x, w0, c2); c2 = f4fma(a2.y, w1, c2);
      c2 = f4fma(a2.z, w2, c2); c2 = f4fma(a2.w, w3, c2);
      c3 = f4fma(a3.x, w0, c3); c3 = f4fma(a3.y, w1, c3);
      c3 = f4fma(a3.z, w2, c3); c3 = f4fma(a3.w, w3, c3);
    }
    int rb = r0 + rg * 4;
    float s0 = c0.x * vsv.x + c0.y * vsv.y + c0.z * vsv.z + c0.w * vsv.w;
    float s1 = c1.x * vsv.x + c1.y * vsv.y + c1.z * vsv.z + c1.w * vsv.w;
    float s2 = c2.x * vsv.x + c2.y * vsv.y + c2.z * vsv.z + c2.w * vsv.w;
    float s3 = c3.x * vsv.x + c3.y * vsv.y + c3.z * vsv.z + c3.w * vsv.w;
    float d0 = c0.x * vdv.x + c0.y * vdv.y + c0.z * vdv.z + c0.w * vdv.w;
    float d1 = c1.x * vdv.x + c1.y * vdv.y + c1.z * vdv.z + c1.w * vdv.w;
    float d2 = c2.x * vdv.x + c2.y * vdv.y + c2.z * vdv.z + c2.w * vdv.w;
    float d3 = c3.x * vdv.x + c3.y * vdv.y + c3.z * vdv.z + c3.w * vdv.w;
    ushort4 pk;
    if (rb + 0 < NN) {
      pk.x = bfbits(c0.x); pk.y = bfbits(c0.y); pk.z = bfbits(c0.z); pk.w = bfbits(c0.w);
      *reinterpret_cast<ushort4*>(&hmat[(size_t)(rb + 0) * 256 + gcol]) = pk;
    }
    if (rb + 1 < NN) {
      pk.x = bfbits(c1.x); pk.y = bfbits(c1.y); pk.z = bfbits(c1.z); pk.w = bfbits(c1.w);
      *reinterpret_cast<ushort4*>(&hmat[(size_t)(rb + 1) * 256 + gcol]) = pk;
    }
    if (rb + 2 < NN) {
      pk.x = bfbits(c2.x); pk.y = bfbits(c2.y); pk.z = bfbits(c2.z); pk.w = bfbits(c2.w);
      *reinterpret_cast<ushort4*>(&hmat[(size_t)(rb + 2) * 256 + gcol]) = pk;
    }
    if (rb + 3 < NN) {
      pk.x = bfbits(c3.x); pk.y = bfbits(c3.y); pk.z = bfbits(c3.z); pk.w = bfbits(c3.w);
      *reinterpret_cast<ushort4*>(&hmat[(size_t)(rb + 3) * 256 + gcol]) = pk;
    }
    for (int o = 1; o < 16; o <<= 1) {
      s0 += __shfl_xor(s0, o); s1 += __shfl_xor(s1, o);
      s2 += __shfl_xor(s2, o); s3 += __shfl_xor(s3, o);
      d0 += __shfl_xor(d0, o); d1 += __shfl_xor(d1, o);
      d2 += __shfl_xor(d2, o); d3 += __shfl_xor(d3, o);
    }
    if ((t & 15) == 0) {
      int h = half * 2 + ((t >> 4) & 1);
      if (rb + 0 < NN) { as_[(rb + 0) * 4 + h] = s0; ad_[(rb + 0) * 4 + h] = d0; }
      if (rb + 1 < NN) { as_[(rb + 1) * 4 + h] = s1; ad_[(rb + 1) * 4 + h] = d1; }
      if (rb + 2 < NN) { as_[(rb + 2) * 4 + h] = s2; ad_[(rb + 2) * 4 + h] = d2; }
      if (rb + 3 < NN) { as_[(rb + 3) * 4 + h] = s3; ad_[(rb + 3) * 4 + h] = d3; }
    }
    __syncthreads();
  }
}

// ---------------------------------------------------------------- GAT
// Wave per dst node. deg<=64 fast path: lane = edge; logits in-register
// (as_[src] gather), wave-reduce max/sum, weights (exp*inv) -> per-wave LDS.
// Pass B: lane owns 4 flat channels (one uint2 bf16x4 load per edge) +
// ds_read_b32 weight (bank-split by head group). Head-mean via shfl_xor.
__global__ __launch_bounds__(256) void k_gat(
    const int* __restrict__ off, const int* __restrict__ csr_src,
    const float* __restrict__ csr_ea, const float* __restrict__ as_,
    const float* __restrict__ ad_, const float* __restrict__ pq, int pqo,
    const bf16* __restrict__ hmat, const float* __restrict__ bias,
    float* __restrict__ out) {
  __shared__ float wlds[4][256];  // per wave: 64 edges x 4 head-weights
  int wv = threadIdx.x >> 6;
  int wid = (blockIdx.x << 2) + wv;
  int lane = threadIdx.x & 63;
  if (wid >= NN) return;
  int beg = off[wid], end = off[wid + 1];
  int deg = end - beg;
  int hsel = lane >> 4;
  float4 D = reinterpret_cast<const float4*>(ad_)[wid];
  float p0 = pq[pqo + 0], p1 = pq[pqo + 1], p2 = pq[pqo + 2], p3 = pq[pqo + 3];
  float q0 = pq[pqo + 4], q1 = pq[pqo + 5], q2 = pq[pqo + 6], q3 = pq[pqo + 7];
  float4 acc = {0.f, 0.f, 0.f, 0.f};

  if (deg <= 64) {
    bool valid = lane < deg;
    float lx = -INFINITY, ly = -INFINITY, lz = -INFINITY, lw = -INFINITY;
    if (valid) {
      int s = csr_src[beg + lane];
      float ea = csr_ea[beg + lane];
      float4 A = reinterpret_cast<const float4*>(as_)[s];
      lx = lrelu(A.x + D.x + ea * p0 + q0);
      ly = lrelu(A.y + D.y + ea * p1 + q1);
      lz = lrelu(A.z + D.z + ea * p2 + q2);
      lw = lrelu(A.w + D.w + ea * p3 + q3);
    }
    float m0 = lx, m1 = ly, m2 = lz, m3 = lw;
    for (int o = 32; o; o >>= 1) {
      m0 = fmaxf(m0, __shfl_xor(m0, o));
      m1 = fmaxf(m1, __shfl_xor(m1, o));
      m2 = fmaxf(m2, __shfl_xor(m2, o));
      m3 = fmaxf(m3, __shfl_xor(m3, o));
    }
    float w0 = valid ? __expf(lx - m0) : 0.f;
    float w1 = valid ? __expf(ly - m1) : 0.f;
    float w2 = valid ? __expf(lz - m2) : 0.f;
    float w3 = valid ? __expf(lw - m3) : 0.f;
    float s0 = w0, s1 = w1, s2 = w2, s3 = w3;
    for (int o = 32; o; o >>= 1) {
      s0 += __shfl_xor(s0, o); s1 += __shfl_xor(s1, o);
      s2 += __shfl_xor(s2, o); s3 += __shfl_xor(s3, o);
    }
    float4 wv4;
    wv4.x = w0 / (s0 + 1e-16f);
    wv4.y = w1 / (s1 + 1e-16f);
    wv4.z = w2 / (s2 + 1e-16f);
    wv4.w = w3 / (s3 + 1e-16f);
    reinterpret_cast<float4*>(&wlds[wv][0])[lane] = wv4;
    const float* wp = &wlds[wv][0];
    int j = 0;
    for (; j + 4 <= deg; j += 4) {
      int sA = csr_src[beg + j + 0];
      int sB = csr_src[beg + j + 1];
      int sC = csr_src[beg + j + 2];
      int sD = csr_src[beg + j + 3];
      float wA = wp[4 * (j + 0) + hsel];
      float wB = wp[4 * (j + 1) + hsel];
      float wC = wp[4 * (j + 2) + hsel];
      float wD = wp[4 * (j + 3) + hsel];
      uint2 uA = *reinterpret_cast<const uint2*>(&hmat[(size_t)sA * 256 + 4 * lane]);
      uint2 uB = *reinterpret_cast<const uint2*>(&hmat[(size_t)sB * 256 + 4 * lane]);
      uint2 uC = *reinterpret_cast<const uint2*>(&hmat[(size_t)sC * 256 + 4 * lane]);
      uint2 uD = *reinterpret_cast<const uint2*>(&hmat[(size_t)sD * 256 + 4 * lane]);
      acc = f4fma(wA, upk4(uA), acc);
      acc = f4fma(wB, upk4(uB), acc);
      acc = f4fma(wC, upk4(uC), acc);
      acc = f4fma(wD, upk4(uD), acc);
    }
    for (; j < deg; ++j) {
      int s = csr_src[beg + j];
      float w = wp[4 * j + hsel];
      uint2 u = *reinterpret_cast<const uint2*>(&hmat[(size_t)s * 256 + 4 * lane]);
      acc = f4fma(w, upk4(u), acc);
    }
  } else {
    // slow fallback for deg > 64 (statistically never for Poisson(8))
    float m0 = -INFINITY, m1 = -INFINITY, m2 = -INFINITY, m3 = -INFINITY;
    float s0 = 0.f, s1 = 0.f, s2 = 0.f, s3 = 0.f;
    for (int e = beg + lane; e < end; e += 64) {
      int s = csr_src[e];
      float ea = csr_ea[e];
      float4 A = reinterpret_cast<const float4*>(as_)[s];
      float lx = lrelu(A.x + D.x + ea * p0 + q0);
      float ly = lrelu(A.y + D.y + ea * p1 + q1);
      float lz = lrelu(A.z + D.z + ea * p2 + q2);
      float lw = lrelu(A.w + D.w + ea * p3 + q3);
      float nm;
      nm = fmaxf(m0, lx); s0 = s0 * __expf(m0 - nm) + __expf(lx - nm); m0 = nm;
      nm = fmaxf(m1, ly); s1 = s1 * __expf(m1 - nm) + __expf(ly - nm); m1 = nm;
      nm = fmaxf(m2, lz); s2 = s2 * __expf(m2 - nm) + __expf(lz - nm); m2 = nm;
      nm = fmaxf(m3, lw); s3 = s3 * __expf(m3 - nm) + __expf(lw - nm); m3 = nm;
    }
    for (int o = 32; o; o >>= 1) {
      float om, os, nm;
      om = __shfl_xor(m0, o); os = __shfl_xor(s0, o); nm = fmaxf(m0, om);
      s0 = s0 * __expf(fmaxf(m0 - nm, -80.f)) + os * __expf(fmaxf(om - nm, -80.f)); m0 = nm;
      om = __shfl_xor(m1, o); os = __shfl_xor(s1, o); nm = fmaxf(m1, om);
      s1 = s1 * __expf(fmaxf(m1 - nm, -80.f)) + os * __expf(fmaxf(om - nm, -80.f)); m1 = nm;
      om = __shfl_xor(m2, o); os = __shfl_xor(s2, o); nm = fmaxf(m2, om);
      s2 = s2 * __expf(fmaxf(m2 - nm, -80.f)) + os * __expf(fmaxf(om - nm, -80.f)); m2 = nm;
      om = __shfl_xor(m3, o); os = __shfl_xor(s3, o); nm = fmaxf(m3, om);
      s3 = s3 * __expf(fmaxf(m3 - nm, -80.f)) + os * __expf(fmaxf(om - nm, -80.f)); m3 = nm;
    }
    float i0 = 1.f / (s0 + 1e-16f), i1 = 1.f / (s1 + 1e-16f);
    float i2 = 1.f / (s2 + 1e-16f), i3 = 1.f / (s3 + 1e-16f);
    float Dh = hsel == 0 ? D.x : hsel == 1 ? D.y : hsel == 2 ? D.z : D.w;
    float ph = hsel == 0 ? p0 : hsel == 1 ? p1 : hsel == 2 ? p2 : p3;
    float qh = hsel == 0 ? q0 : hsel == 1 ? q1 : hsel == 2 ? q2 : q3;
    float mh = hsel == 0 ? m0 : hsel == 1 ? m1 : hsel == 2 ? m2 : m3;
    float ih = hsel == 0 ? i0 : hsel == 1 ? i1 : hsel == 2 ? i2 : i3;
    for (int j = beg; j < end; ++j) {
      int s = csr_src[j];
      float ea = csr_ea[j];
      float4 A = reinterpret_cast<const float4*>(as_)[s];
      float Ah = hsel == 0 ? A.x : hsel == 1 ? A.y : hsel == 2 ? A.z : A.w;
      float l = lrelu(Ah + Dh + ea * ph + qh);
      float w = __expf(l - mh) * ih;
      uint2 u = *reinterpret_cast<const uint2*>(&hmat[(size_t)s * 256 + 4 * lane]);
      acc = f4fma(w, upk4(u), acc);
    }
  }
  // reduce across heads: lanes g, g+16, g+32, g+48 hold heads 0..3 of the
  // same 4-channel group g = lane & 15
  acc.x += __shfl_xor(acc.x, 16); acc.y += __shfl_xor(acc.y, 16);
  acc.z += __shfl_xor(acc.z, 16); acc.w += __shfl_xor(acc.w, 16);
  acc.x += __shfl_xor(acc.x, 32); acc.y += __shfl_xor(acc.y, 32);
  acc.z += __shfl_xor(acc.z, 32); acc.w += __shfl_xor(acc.w, 32);
  if (lane < 16) {
    float4 bv = reinterpret_cast<const float4*>(bias)[lane];
    float4 r;
    r.x = eluf(0.25f * acc.x + bv.x);
    r.y = eluf(0.25f * acc.y + bv.y);
    r.z = eluf(0.25f * acc.z + bv.z);
    r.w = eluf(0.25f * acc.w + bv.w);
    reinterpret_cast<float4*>(&out[(size_t)wid * 64])[lane] = r;
  }
}

// ---------------------------------------------------------------- SAGE agg
// Pure gather: wave per node, lane = channel, mean of h3[src]. No LDS.
__global__ __launch_bounds__(256) void k_agg(
    const int* __restrict__ off, const int* __restrict__ csr_src,
    const float* __restrict__ h3, float* __restrict__ agg) {
  int wid = (blockIdx.x << 2) + (threadIdx.x >> 6);
  int lane = threadIdx.x & 63;
  if (wid >= NN) return;
  int beg = off[wid], end = off[wid + 1];
  float acc = 0.f;
  int e = beg;
  for (; e + 4 <= end; e += 4) {
    int s0 = csr_src[e + 0], s1 = csr_src[e + 1];
    int s2 = csr_src[e + 2], s3 = csr_src[e + 3];
    float v0 = h3[(size_t)s0 * 64 + lane];
    float v1 = h3[(size_t)s1 * 64 + lane];
    float v2 = h3[(size_t)s2 * 64 + lane];
    float v3 = h3[(size_t)s3 * 64 + lane];
    acc += (v0 + v1) + (v2 + v3);
  }
  for (; e < end; ++e) acc += h3[(size_t)csr_src[e] * 64 + lane];
  agg[(size_t)wid * 64 + lane] = acc / fmaxf((float)(end - beg), 1.f);
}

// ---------------------------------------------------------------- SAGE GEMM
// out[n] = elu(agg[n]@Wl + h[n]@Wr + b). Block: 32 rows; thread 2 rows x 4 cols.
__global__ __launch_bounds__(256) void k_sage_mm(
    const float* __restrict__ agg, const float* __restrict__ h3,
    const float* __restrict__ Wl, const float* __restrict__ Wr,
    const float* __restrict__ bias, float* __restrict__ out) {
  __shared__ float WlS[4096];
  __shared__ float WrS[4096];
  __shared__ float Ag[2048];
  __shared__ float Hr[2048];
  int t = threadIdx.x;
  for (int i = t; i < 4096; i += 256) { WlS[i] = Wl[i]; WrS[i] = Wr[i]; }
  int ct = t & 15, rg = t >> 4;
  float4 bv = reinterpret_cast<const float4*>(bias)[ct];
  for (int r0 = blockIdx.x * 32; r0 < NN; r0 += gridDim.x * 32) {
    for (int i = t; i < 2048; i += 256) {
      int n = r0 + (i >> 6);
      float va = 0.f, vh = 0.f;
      if (n < NN) {
        va = agg[(size_t)n * 64 + (i & 63)];
        vh = h3[(size_t)n * 64 + (i & 63)];
      }
      Ag[i] = va; Hr[i] = vh;
    }
    __syncthreads();
    float4 c0 = {0.f, 0.f, 0.f, 0.f}, c1 = c0;
    const float* a0 = &Ag[(rg * 2 + 0) * 64];
    const float* a1 = &Ag[(rg * 2 + 1) * 64];
    const float* h0 = &Hr[(rg * 2 + 0) * 64];
    const float* h1 = &Hr[(rg * 2 + 1) * 64];
    #pragma unroll 4
    for (int k = 0; k < 64; k += 4) {
      float4 wl0 = *reinterpret_cast<const float4*>(&WlS[(k + 0) * 64 + ct * 4]);
      float4 wl1 = *reinterpret_cast<const float4*>(&WlS[(k + 1) * 64 + ct * 4]);
      float4 wl2 = *reinterpret_cast<const float4*>(&WlS[(k + 2) * 64 + ct * 4]);
      float4 wl3 = *reinterpret_cast<const float4*>(&WlS[(k + 3) * 64 + ct * 4]);
      float4 wr0 = *reinterpret_cast<const float4*>(&WrS[(k + 0) * 64 + ct * 4]);
      float4 wr1 = *reinterpret_cast<const float4*>(&WrS[(k + 1) * 64 + ct * 4]);
      float4 wr2 = *reinterpret_cast<const float4*>(&WrS[(k + 2) * 64 + ct * 4]);
      float4 wr3 = *reinterpret_cast<const float4*>(&WrS[(k + 3) * 64 + ct * 4]);
      float4 aa0 = *reinterpret_cast<const float4*>(&a0[k]);
      float4 aa1 = *reinterpret_cast<const float4*>(&a1[k]);
      float4 hh0 = *reinterpret_cast<const float4*>(&h0[k]);
      float4 hh1 = *reinterpret_cast<const float4*>(&h1[k]);
      c0 = f4fma(aa0.x, wl0, c0); c0 = f4fma(aa0.y, wl1, c0);
      c0 = f4fma(aa0.z, wl2, c0); c0 = f4fma(aa0.w, wl3, c0);
      c0 = f4fma(hh0.x, wr0, c0); c0 = f4fma(hh0.y, wr1, c0);
      c0 = f4fma(hh0.z, wr2, c0); c0 = f4fma(hh0.w, wr3, c0);
      c1 = f4fma(aa1.x, wl0, c1); c1 = f4fma(aa1.y, wl1, c1);
      c1 = f4fma(aa1.z, wl2, c1); c1 = f4fma(aa1.w, wl3, c1);
      c1 = f4fma(hh1.x, wr0, c1); c1 = f4fma(hh1.y, wr1, c1);
      c1 = f4fma(hh1.z, wr2, c1); c1 = f4fma(hh1.w, wr3, c1);
    }
    int n0 = r0 + rg * 2;
    if (n0 + 0 < NN) {
      float4 r;
      r.x = eluf(c0.x + bv.x); r.y = eluf(c0.y + bv.y);
      r.z = eluf(c0.z + bv.z); r.w = eluf(c0.w + bv.w);
      *reinterpret_cast<float4*>(&out[(size_t)(n0 + 0) * 64 + ct * 4]) = r;
    }
    if (n0 + 1 < NN) {
      float4 r;
      r.x = eluf(c1.x + bv.x); r.y = eluf(c1.y + bv.y);
      r.z = eluf(c1.z + bv.z); r.w = eluf(c1.w + bv.w);
      *reinterpret_cast<float4*>(&out[(size_t)(n0 + 1) * 64 + ct * 4]) = r;
    }
    __syncthreads();
  }
}

// ---------------------------------------------------------------- pooling
__device__ __forceinline__ int lowerb(const int* __restrict__ a, int n, int key) {
  int lo = 0, hi = n;
  while (lo < hi) { int mid = (lo + hi) >> 1; if (a[mid] < key) lo = mid + 1; else hi = mid; }
  return lo;
}

__global__ __launch_bounds__(256) void k_pool(const float* __restrict__ hs,
                                              const int* __restrict__ batch,
                                              float* __restrict__ g) {
  int b = blockIdx.x;
  int lo = lowerb(batch, NN, b), hi = lowerb(batch, NN, b + 1);
  int t = threadIdx.x, lane = t & 63, w = t >> 6;
  float acc = 0.f;
  for (int n = lo + w; n < hi; n += 4) acc += hs[(size_t)n * 64 + lane];
  __shared__ float red[4][64];
  red[w][lane] = acc;
  __syncthreads();
  if (w == 0) {
    float v = red[0][lane] + red[1][lane] + red[2][lane] + red[3][lane];
    g[b * 64 + lane] = v / fmaxf((float)(hi - lo), 1.f);
  }
}

// ---------------------------------------------------------------- MLP head
__global__ __launch_bounds__(256) void k_head(
    const float* __restrict__ g, const float* __restrict__ l1W,
    const float* __restrict__ l1b, const float* __restrict__ l2W,
    const float* __restrict__ l2b, const float* __restrict__ telW,
    const float* __restrict__ telb, const float* __restrict__ compW,
    const float* __restrict__ compb, const float* __restrict__ pchW,
    const float* __restrict__ pchb, float* __restrict__ out) {
  __shared__ float gS[4096];
  __shared__ float WS[4096];
  __shared__ float hS[4096];
  int t = threadIdx.x;
  for (int i = t; i < 4096; i += 256) { gS[i] = g[i]; WS[i] = l1W[i]; }
  __syncthreads();
  for (int i = t; i < 4096; i += 256) {
    int r = i >> 6, j = i & 63;
    float s = 0.f;
    for (int k = 0; k < 64; ++k) s += gS[r * 64 + k] * WS[k * 64 + j];
    hS[i] = eluf(s + l1b[j]);
  }
  __syncthreads();
  for (int i = t; i < 4096; i += 256) WS[i] = l2W[i];
  __syncthreads();
  for (int i = t; i < 4096; i += 256) {
    int r = i >> 6, j = i & 63;
    float s = 0.f;
    for (int k = 0; k < 64; ++k) s += hS[r * 64 + k] * WS[k * 64 + j];
    gS[i] = s + l2b[j];
  }
  __syncthreads();
  if (t < 192) {
    int head = t >> 6, r = t & 63;
    const float* Wv = head == 0 ? telW : (head == 1 ? compW : pchW);
    float bb = head == 0 ? telb[0] : (head == 1 ? compb[0] : pchb[0]);
    float s = 0.f;
    for (int k = 0; k < 64; ++k) s += gS[r * 64 + k] * Wv[k];
    out[t] = s + bb;
  }
}

// ---------------------------------------------------------------- launch
extern "C" void kernel_launch(void* const* d_in, const int* in_sizes, int n_in,
                              void* d_out, int out_size, void* d_ws, size_t ws_size,
                              hipStream_t stream) {
  const float* x     = (const float*)d_in[0];
  const int*   eidx  = (const int*)d_in[1];
  const float* eattr = (const float*)d_in[2];
  const int*   batch = (const int*)d_in[3];
  const int*   ntype = (const int*)d_in[4];
  const float* nemb  = (const float*)d_in[5];
  const float* edgeW = (const float*)d_in[6];
  const float* edgeB = (const float*)d_in[7];
  const float* W1    = (const float*)d_in[8];
  const float* atts1 = (const float*)d_in[9];
  const float* attd1 = (const float*)d_in[10];
  const float* We1   = (const float*)d_in[11];
  const float* atte1 = (const float*)d_in[12];
  const float* b1    = (const float*)d_in[13];
  const float* W2    = (const float*)d_in[14];
  const float* atts2 = (const float*)d_in[15];
  const float* attd2 = (const float*)d_in[16];
  const float* We2   = (const float*)d_in[17];
  const float* atte2 = (const float*)d_in[18];
  const float* b2    = (const float*)d_in[19];
  const float* sageWl = (const float*)d_in[20];
  const float* sageWr = (const float*)d_in[21];
  const float* sageB  = (const float*)d_in[22];
  const float* l1W = (const float*)d_in[23];
  const float* l1b = (const float*)d_in[24];
  const float* l2W = (const float*)d_in[25];
  const float* l2b = (const float*)d_in[26];
  const float* telW  = (const float*)d_in[27];
  const float* telb  = (const float*)d_in[28];
  const float* compW = (const float*)d_in[29];
  const float* compb = (const float*)d_in[30];
  const float* pchW  = (const float*)d_in[31];
  const float* pchb  = (const float*)d_in[32];

  char* wp = (char*)d_ws;
  auto alloc = [&](size_t bytes) -> char* {
    char* p = wp;
    wp += (bytes + 255) & ~(size_t)255;
    return p;
  };
  float*  pq      = (float*)alloc(16 * 4);
  int*    cnt     = (int*)alloc((size_t)NN * 4);
  int*    off     = (int*)alloc(((size_t)NN + 1) * 4);
  int*    csr_src = (int*)alloc((size_t)NE * 4);
  float*  csr_ea  = (float*)alloc((size_t)NE * 4);
  float*  as_     = (float*)alloc((size_t)NN * 16);
  float*  ad_     = (float*)alloc((size_t)NN * 16);
  bf16*   hmat    = (bf16*)alloc((size_t)NN * 256 * 2);
  float*  nodeA   = (float*)alloc((size_t)NN * 64 * 4);
  float*  nodeB   = (float*)alloc((size_t)NN * 64 * 4);
  float*  aggbuf  = (float*)alloc((size_t)NN * 64 * 4);
  float*  gbuf    = (float*)alloc(64 * 64 * 4);

  const int* srcI = eidx;
  const int* dstI = eidx + NE;

  hipMemsetAsync(cnt, 0, (size_t)NN * 4, stream);
  k_pq<<<1, 256, 0, stream>>>(We1, atte1, We2, atte2, edgeW, edgeB, pq);
  k_hist<<<(NE + 255) / 256, 256, 0, stream>>>(dstI, cnt);
  k_scan<<<1, 1024, 0, stream>>>(cnt, off);
  hipMemsetAsync(cnt, 0, (size_t)NN * 4, stream);
  k_scatter<<<(NE + 255) / 256, 256, 0, stream>>>(srcI, dstI, eattr, off, cnt,
                                                  csr_src, csr_ea);
  // GAT layer 1
  k_gemm_att<96, true><<<1024, 256, 0, stream>>>(
      x, ntype, nemb, nullptr, W1, atts1, attd1, hmat, as_, ad_);
  k_gat<<<NN / 4, 256, 0, stream>>>(off, csr_src, csr_ea, as_, ad_, pq, 0,
                                    hmat, b1, nodeA);
  // GAT layer 2
  k_gemm_att<64, false><<<1024, 256, 0, stream>>>(
      nullptr, nullptr, nullptr, nodeA, W2, atts2, attd2, hmat, as_, ad_);
  k_gat<<<NN / 4, 256, 0, stream>>>(off, csr_src, csr_ea, as_, ad_, pq, 8,
                                    hmat, b2, nodeB);
  // SAGE + pool + head
  k_agg<<<NN / 4, 256, 0, stream>>>(off, csr_src, nodeB, aggbuf);
  k_sage_mm<<<1024, 256, 0, stream>>>(aggbuf, nodeB, sageWl, sageWr, sageB,
                                      nodeA);
  k_pool<<<NBATCH, 256, 0, stream>>>(nodeA, batch, gbuf);
  k_head<<<1, 256, 0, stream>>>(gbuf, l1W, l1b, l2W, l2b, telW, telb, compW,
                                compb, pchW, pchb, (float*)d_out);
}

// Round 7
// 490.327 us; speedup vs baseline: 1.6277x; 1.1088x over previous
//
#include <hip/hip_runtime.h>
#include <hip/hip_bf16.h>

// EnhancedTelomeraseGNN on MI355X — round 7.
// f32 in/out. GEMMs moved to MFMA (16x16x32 bf16) with split-bf16 operands
// (hi+lo planes, 3 mfmas/K-step: hi*hi + lo*hi + hi*lo) -> f32-equivalent
// precision. Zero LDS in GEMM; fragments loaded directly from global planes.
// k-fill uses contiguous k=(lane>>4)*8+j for BOTH A and B (any consistent
// bijection is correct); C/D: col=lane&15, row=(lane>>4)*4+reg [HW-verified].
// a_e = ea*p[h] + q[h] collapse retained. hmat bf16 messages; scores f32.
//
// Workspace (~76 MB, overlaid): pq | cnt | off | csr_src | csr_ea | as | ad |
// hmat bf16[N,256] | nodeB f32[N,64] | agg f32[N,64] | B-planes | R(19.2MB):
// A1 planes -> A2 planes -> sage-out f32.

#define NN 50000
#define NE 400000
#define FIN 32
#define NBATCH 64

typedef __hip_bfloat16 bf16;
typedef short bf16x8 __attribute__((ext_vector_type(8)));
typedef float f32x4 __attribute__((ext_vector_type(4)));

__device__ __forceinline__ float b2f(bf16 v) { return __bfloat162float(v); }
__device__ __forceinline__ float lrelu(float x) { return x > 0.f ? x : 0.2f * x; }
__device__ __forceinline__ float eluf(float x) { return x > 0.f ? x : (expf(x) - 1.f); }

__device__ __forceinline__ float4 f4fma(float s, float4 w, float4 c) {
  c.x = fmaf(s, w.x, c.x); c.y = fmaf(s, w.y, c.y);
  c.z = fmaf(s, w.z, c.z); c.w = fmaf(s, w.w, c.w);
  return c;
}

__device__ __forceinline__ float4 upk4(uint2 u) {
  float4 f;
  f.x = __uint_as_float(u.x << 16);
  f.y = __uint_as_float(u.x & 0xffff0000u);
  f.z = __uint_as_float(u.y << 16);
  f.w = __uint_as_float(u.y & 0xffff0000u);
  return f;
}

__device__ __forceinline__ unsigned short bfbits(float f) {
  bf16 b = __float2bfloat16(f);
  unsigned short u;
  __builtin_memcpy(&u, &b, 2);
  return u;
}
__device__ __forceinline__ float hi_f(unsigned short u) {
  return __uint_as_float((unsigned int)u << 16);
}

// ---------------------------------------------------------------- p/q scalars
__global__ __launch_bounds__(256) void k_pq(
    const float* __restrict__ We1, const float* __restrict__ atte1,
    const float* __restrict__ We2, const float* __restrict__ atte2,
    const float* __restrict__ edgeW, const float* __restrict__ edgeB,
    float* __restrict__ pq) {
  int t = threadIdx.x, h = t >> 6, c = t & 63;
  float sW1 = 0.f, sB1 = 0.f, sW2 = 0.f, sB2 = 0.f;
  for (int j = 0; j < 64; ++j) {
    float w = edgeW[j], b = edgeB[j];
    float we1 = We1[j * 256 + h * 64 + c];
    float we2 = We2[j * 256 + h * 64 + c];
    sW1 += w * we1; sB1 += b * we1;
    sW2 += w * we2; sB2 += b * we2;
  }
  float a1 = atte1[h * 64 + c], a2 = atte2[h * 64 + c];
  float p1 = sW1 * a1, q1 = sB1 * a1, p2 = sW2 * a2, q2 = sB2 * a2;
  for (int o = 32; o; o >>= 1) {
    p1 += __shfl_xor(p1, o); q1 += __shfl_xor(q1, o);
    p2 += __shfl_xor(p2, o); q2 += __shfl_xor(q2, o);
  }
  if (c == 0) { pq[h] = p1; pq[4 + h] = q1; pq[8 + h] = p2; pq[12 + h] = q2; }
}

// ---------------------------------------------------------------- CSR build
__global__ void k_hist(const int* __restrict__ dst, int* __restrict__ cnt) {
  int e = blockIdx.x * 256 + threadIdx.x;
  if (e < NE) atomicAdd(&cnt[dst[e]], 1);
}

__global__ __launch_bounds__(1024) void k_scan(const int* __restrict__ cnt,
                                               int* __restrict__ off) {
  __shared__ int wsum[16];
  __shared__ int carry;
  int t = threadIdx.x, lane = t & 63, w = t >> 6;
  if (t == 0) { carry = 0; off[0] = 0; }
  __syncthreads();
  for (int base = 0; base < NN; base += 1024) {
    int idx = base + t;
    int v = (idx < NN) ? cnt[idx] : 0;
    int s = v;
    for (int o = 1; o < 64; o <<= 1) { int u = __shfl_up(s, o); if (lane >= o) s += u; }
    if (lane == 63) wsum[w] = s;
    __syncthreads();
    if (t < 16) {
      int ws = wsum[t];
      for (int o = 1; o < 16; o <<= 1) { int u = __shfl_up(ws, o); if (t >= o) ws += u; }
      wsum[t] = ws;
    }
    __syncthreads();
    int add = carry + (w ? wsum[w - 1] : 0);
    if (idx < NN) off[idx + 1] = add + s;
    __syncthreads();
    if (t == 0) carry += wsum[15];
    __syncthreads();
  }
}

__global__ void k_scatter(const int* __restrict__ src, const int* __restrict__ dst,
                          const float* __restrict__ ea, const int* __restrict__ off,
                          int* __restrict__ cur, int* __restrict__ csr_src,
                          float* __restrict__ csr_ea) {
  int e = blockIdx.x * 256 + threadIdx.x;
  if (e >= NE) return;
  int d = dst[e];
  int slot = off[d] + atomicAdd(&cur[d], 1);
  csr_src[slot] = src[e];
  csr_ea[slot] = ea[e];
}

// ---------------------------------------------------------------- split prep
// A1 planes [NN][96] from concat(x, emb[ntype]); hi = RNE(v), lo = RNE(v-hi).
__global__ __launch_bounds__(256) void k_splitA(
    const float* __restrict__ x, const int* __restrict__ ntype,
    const float* __restrict__ emb, unsigned short* __restrict__ Ah,
    unsigned short* __restrict__ Al) {
  const int total = NN * 96;
  for (int i = blockIdx.x * 256 + threadIdx.x; i < total; i += gridDim.x * 256) {
    int n = i / 96, k = i - n * 96;
    float v = (k < FIN) ? x[n * FIN + k] : emb[ntype[n] * 64 + (k - FIN)];
    unsigned short h = bfbits(v);
    Ah[i] = h;
    Al[i] = bfbits(v - hi_f(h));
  }
}

// W1^T [256][96] and W2^T [256][64] hi/lo planes.
__global__ __launch_bounds__(256) void k_splitW(
    const float* __restrict__ W1, const float* __restrict__ W2,
    unsigned short* __restrict__ B1h, unsigned short* __restrict__ B1l,
    unsigned short* __restrict__ B2h, unsigned short* __restrict__ B2l) {
  int t = blockIdx.x * 256 + threadIdx.x;
  if (t < 256 * 96) {
    int n = t / 96, k = t - n * 96;
    float v = W1[k * 256 + n];
    unsigned short h = bfbits(v);
    B1h[t] = h; B1l[t] = bfbits(v - hi_f(h));
  }
  if (t < 256 * 64) {
    int n = t >> 6, k = t & 63;
    float v = W2[k * 256 + n];
    unsigned short h = bfbits(v);
    B2h[t] = h; B2l[t] = bfbits(v - hi_f(h));
  }
}

// ---------------------------------------------------------------- MFMA GEMM
// hmat[m,0:256] = A[m,0:K] @ W[K,256] via split-bf16 (3 mfmas per K-step).
// Block = 64 rows x 256 cols; wave w = head w (cols w*64..+63), 4x4 tiles of
// 16x16x32. Fragments from global planes (no LDS). Fused epilogue: hmat bf16
// + as_/ad_ head scores from f32 accumulators.
template <int K>
__global__ __launch_bounds__(256) void k_mm_mfma(
    const unsigned short* __restrict__ Ah, const unsigned short* __restrict__ Al,
    const unsigned short* __restrict__ Bh, const unsigned short* __restrict__ Bl,
    const float* __restrict__ atts, const float* __restrict__ attd,
    bf16* __restrict__ hmat, float* __restrict__ as_, float* __restrict__ ad_) {
  int m0 = blockIdx.x * 64;
  int w = threadIdx.x >> 6;     // wave = head
  int lane = threadIdx.x & 63;
  int lr = lane & 15;           // A row-in-tile / B col-in-tile
  int lc = lane >> 4;           // k-block selector
  float attsv[4], attdv[4];
  #pragma unroll
  for (int nt = 0; nt < 4; ++nt) {
    attsv[nt] = atts[w * 64 + nt * 16 + lr];
    attdv[nt] = attd[w * 64 + nt * 16 + lr];
  }
  f32x4 acc[4][4] = {};
  #pragma unroll
  for (int ks = 0; ks < K; ks += 32) {
    int koff = ks + lc * 8;
    bf16x8 ah[4], al[4], bh[4], bl[4];
    #pragma unroll
    for (int mt = 0; mt < 4; ++mt) {
      int m = m0 + mt * 16 + lr;
      if (m > NN - 1) m = NN - 1;           // clamp: garbage rows are never stored
      ah[mt] = *reinterpret_cast<const bf16x8*>(&Ah[(size_t)m * K + koff]);
      al[mt] = *reinterpret_cast<const bf16x8*>(&Al[(size_t)m * K + koff]);
    }
    #pragma unroll
    for (int nt = 0; nt < 4; ++nt) {
      int n = w * 64 + nt * 16 + lr;
      bh[nt] = *reinterpret_cast<const bf16x8*>(&Bh[(size_t)n * K + koff]);
      bl[nt] = *reinterpret_cast<const bf16x8*>(&Bl[(size_t)n * K + koff]);
    }
    #pragma unroll
    for (int mt = 0; mt < 4; ++mt) {
      #pragma unroll
      for (int nt = 0; nt < 4; ++nt) {
        acc[mt][nt] = __builtin_amdgcn_mfma_f32_16x16x32_bf16(ah[mt], bh[nt], acc[mt][nt], 0, 0, 0);
        acc[mt][nt] = __builtin_amdgcn_mfma_f32_16x16x32_bf16(al[mt], bh[nt], acc[mt][nt], 0, 0, 0);
        acc[mt][nt] = __builtin_amdgcn_mfma_f32_16x16x32_bf16(ah[mt], bl[nt], acc[mt][nt], 0, 0, 0);
      }
    }
  }
  // epilogue: C[row][col], col = w*64 + nt*16 + lr, row = m0 + mt*16 + lc*4 + reg
  #pragma unroll
  for (int mt = 0; mt < 4; ++mt) {
    #pragma unroll
    for (int reg = 0; reg < 4; ++reg) {
      int row = m0 + mt * 16 + lc * 4 + reg;
      float sS = 0.f, sD = 0.f;
      #pragma unroll
      for (int nt = 0; nt < 4; ++nt) {
        float v = acc[mt][nt][reg];
        sS += v * attsv[nt];
        sD += v * attdv[nt];
      }
      // reduce over the 16 lanes of this row group (lane>>4 fixed)
      for (int o = 1; o < 16; o <<= 1) {
        sS += __shfl_xor(sS, o);
        sD += __shfl_xor(sD, o);
      }
      if (row < NN) {
        #pragma unroll
        for (int nt = 0; nt < 4; ++nt)
          hmat[(size_t)row * 256 + w * 64 + nt * 16 + lr] =
              __float2bfloat16(acc[mt][nt][reg]);
        if (lr == 0) { as_[row * 4 + w] = sS; ad_[row * 4 + w] = sD; }
      }
    }
  }
}

// ---------------------------------------------------------------- GAT
// Wave per dst node. deg<=64 fast path: lane = edge; logits in-register,
// wave-reduce max/sum, weights -> per-wave LDS. Pass B: lane owns 4 flat
// channels (uint2 bf16x4 per edge) + ds weight; head-mean via shfl_xor.
// Output: f32 (outf) and/or split-bf16 planes (oph/opl) for the next GEMM.
__global__ __launch_bounds__(256) void k_gat(
    const int* __restrict__ off, const int* __restrict__ csr_src,
    const float* __restrict__ csr_ea, const float* __restrict__ as_,
    const float* __restrict__ ad_, const float* __restrict__ pq, int pqo,
    const bf16* __restrict__ hmat, const float* __restrict__ bias,
    float* __restrict__ outf, unsigned short* __restrict__ oph,
    unsigned short* __restrict__ opl) {
  __shared__ float wlds[4][256];
  int wv = threadIdx.x >> 6;
  int wid = (blockIdx.x << 2) + wv;
  int lane = threadIdx.x & 63;
  if (wid >= NN) return;
  int beg = off[wid], end = off[wid + 1];
  int deg = end - beg;
  int hsel = lane >> 4;
  float4 D = reinterpret_cast<const float4*>(ad_)[wid];
  float p0 = pq[pqo + 0], p1 = pq[pqo + 1], p2 = pq[pqo + 2], p3 = pq[pqo + 3];
  float q0 = pq[pqo + 4], q1 = pq[pqo + 5], q2 = pq[pqo + 6], q3 = pq[pqo + 7];
  float4 acc = {0.f, 0.f, 0.f, 0.f};

  if (deg <= 64) {
    bool valid = lane < deg;
    float lx = -INFINITY, ly = -INFINITY, lz = -INFINITY, lw = -INFINITY;
    if (valid) {
      int s = csr_src[beg + lane];
      float ea = csr_ea[beg + lane];
      float4 A = reinterpret_cast<const float4*>(as_)[s];
      lx = lrelu(A.x + D.x + ea * p0 + q0);
      ly = lrelu(A.y + D.y + ea * p1 + q1);
      lz = lrelu(A.z + D.z + ea * p2 + q2);
      lw = lrelu(A.w + D.w + ea * p3 + q3);
    }
    float m0 = lx, m1 = ly, m2 = lz, m3 = lw;
    for (int o = 32; o; o >>= 1) {
      m0 = fmaxf(m0, __shfl_xor(m0, o));
      m1 = fmaxf(m1, __shfl_xor(m1, o));
      m2 = fmaxf(m2, __shfl_xor(m2, o));
      m3 = fmaxf(m3, __shfl_xor(m3, o));
    }
    float w0 = valid ? __expf(lx - m0) : 0.f;
    float w1 = valid ? __expf(ly - m1) : 0.f;
    float w2 = valid ? __expf(lz - m2) : 0.f;
    float w3 = valid ? __expf(lw - m3) : 0.f;
    float s0 = w0, s1 = w1, s2 = w2, s3 = w3;
    for (int o = 32; o; o >>= 1) {
      s0 += __shfl_xor(s0, o); s1 += __shfl_xor(s1, o);
      s2 += __shfl_xor(s2, o); s3 += __shfl_xor(s3, o);
    }
    float4 wv4;
    wv4.x = w0 / (s0 + 1e-16f);
    wv4.y = w1 / (s1 + 1e-16f);
    wv4.z = w2 / (s2 + 1e-16f);
    wv4.w = w3 / (s3 + 1e-16f);
    reinterpret_cast<float4*>(&wlds[wv][0])[lane] = wv4;
    const float* wp = &wlds[wv][0];
    int j = 0;
    for (; j + 4 <= deg; j += 4) {
      int sA = csr_src[beg + j + 0];
      int sB = csr_src[beg + j + 1];
      int sC = csr_src[beg + j + 2];
      int sD = csr_src[beg + j + 3];
      float wA = wp[4 * (j + 0) + hsel];
      float wB = wp[4 * (j + 1) + hsel];
      float wC = wp[4 * (j + 2) + hsel];
      float wD = wp[4 * (j + 3) + hsel];
      uint2 uA = *reinterpret_cast<const uint2*>(&hmat[(size_t)sA * 256 + 4 * lane]);
      uint2 uB = *reinterpret_cast<const uint2*>(&hmat[(size_t)sB * 256 + 4 * lane]);
      uint2 uC = *reinterpret_cast<const uint2*>(&hmat[(size_t)sC * 256 + 4 * lane]);
      uint2 uD = *reinterpret_cast<const uint2*>(&hmat[(size_t)sD * 256 + 4 * lane]);
      acc = f4fma(wA, upk4(uA), acc);
      acc = f4fma(wB, upk4(uB), acc);
      acc = f4fma(wC, upk4(uC), acc);
      acc = f4fma(wD, upk4(uD), acc);
    }
    for (; j < deg; ++j) {
      int s = csr_src[beg + j];
      float w = wp[4 * j + hsel];
      uint2 u = *reinterpret_cast<const uint2*>(&hmat[(size_t)s * 256 + 4 * lane]);
      acc = f4fma(w, upk4(u), acc);
    }
  } else {
    float m0 = -INFINITY, m1 = -INFINITY, m2 = -INFINITY, m3 = -INFINITY;
    float s0 = 0.f, s1 = 0.f, s2 = 0.f, s3 = 0.f;
    for (int e = beg + lane; e < end; e += 64) {
      int s = csr_src[e];
      float ea = csr_ea[e];
      float4 A = reinterpret_cast<const float4*>(as_)[s];
      float lx = lrelu(A.x + D.x + ea * p0 + q0);
      float ly = lrelu(A.y + D.y + ea * p1 + q1);
      float lz = lrelu(A.z + D.z + ea * p2 + q2);
      float lw = lrelu(A.w + D.w + ea * p3 + q3);
      float nm;
      nm = fmaxf(m0, lx); s0 = s0 * __expf(m0 - nm) + __expf(lx - nm); m0 = nm;
      nm = fmaxf(m1, ly); s1 = s1 * __expf(m1 - nm) + __expf(ly - nm); m1 = nm;
      nm = fmaxf(m2, lz); s2 = s2 * __expf(m2 - nm) + __expf(lz - nm); m2 = nm;
      nm = fmaxf(m3, lw); s3 = s3 * __expf(m3 - nm) + __expf(lw - nm); m3 = nm;
    }
    for (int o = 32; o; o >>= 1) {
      float om, os, nm;
      om = __shfl_xor(m0, o); os = __shfl_xor(s0, o); nm = fmaxf(m0, om);
      s0 = s0 * __expf(fmaxf(m0 - nm, -80.f)) + os * __expf(fmaxf(om - nm, -80.f)); m0 = nm;
      om = __shfl_xor(m1, o); os = __shfl_xor(s1, o); nm = fmaxf(m1, om);
      s1 = s1 * __expf(fmaxf(m1 - nm, -80.f)) + os * __expf(fmaxf(om - nm, -80.f)); m1 = nm;
      om = __shfl_xor(m2, o); os = __shfl_xor(s2, o); nm = fmaxf(m2, om);
      s2 = s2 * __expf(fmaxf(m2 - nm, -80.f)) + os * __expf(fmaxf(om - nm, -80.f)); m2 = nm;
      om = __shfl_xor(m3, o); os = __shfl_xor(s3, o); nm = fmaxf(m3, om);
      s3 = s3 * __expf(fmaxf(m3 - nm, -80.f)) + os * __expf(fmaxf(om - nm, -80.f)); m3 = nm;
    }
    float i0 = 1.f / (s0 + 1e-16f), i1 = 1.f / (s1 + 1e-16f);
    float i2 = 1.f / (s2 + 1e-16f), i3 = 1.f / (s3 + 1e-16f);
    float Dh = hsel == 0 ? D.x : hsel == 1 ? D.y : hsel == 2 ? D.z : D.w;
    float ph = hsel == 0 ? p0 : hsel == 1 ? p1 : hsel == 2 ? p2 : p3;
    float qh = hsel == 0 ? q0 : hsel == 1 ? q1 : hsel == 2 ? q2 : q3;
    float mh = hsel == 0 ? m0 : hsel == 1 ? m1 : hsel == 2 ? m2 : m3;
    float ih = hsel == 0 ? i0 : hsel == 1 ? i1 : hsel == 2 ? i2 : i3;
    for (int j = beg; j < end; ++j) {
      int s = csr_src[j];
      float ea = csr_ea[j];
      float4 A = reinterpret_cast<const float4*>(as_)[s];
      float Ah = hsel == 0 ? A.x : hsel == 1 ? A.y : hsel == 2 ? A.z : A.w;
      float l = lrelu(Ah + Dh + ea * ph + qh);
      float w = __expf(l - mh) * ih;
      uint2 u = *reinterpret_cast<const uint2*>(&hmat[(size_t)s * 256 + 4 * lane]);
      acc = f4fma(w, upk4(u), acc);
    }
  }
  acc.x += __shfl_xor(acc.x, 16); acc.y += __shfl_xor(acc.y, 16);
  acc.z += __shfl_xor(acc.z, 16); acc.w += __shfl_xor(acc.w, 16);
  acc.x += __shfl_xor(acc.x, 32); acc.y += __shfl_xor(acc.y, 32);
  acc.z += __shfl_xor(acc.z, 32); acc.w += __shfl_xor(acc.w, 32);
  if (lane < 16) {
    float4 bv = reinterpret_cast<const float4*>(bias)[lane];
    float4 r;
    r.x = eluf(0.25f * acc.x + bv.x);
    r.y = eluf(0.25f * acc.y + bv.y);
    r.z = eluf(0.25f * acc.z + bv.z);
    r.w = eluf(0.25f * acc.w + bv.w);
    if (outf) reinterpret_cast<float4*>(&outf[(size_t)wid * 64])[lane] = r;
    if (oph) {
      ushort4 h4, l4;
      h4.x = bfbits(r.x); l4.x = bfbits(r.x - hi_f(h4.x));
      h4.y = bfbits(r.y); l4.y = bfbits(r.y - hi_f(h4.y));
      h4.z = bfbits(r.z); l4.z = bfbits(r.z - hi_f(h4.z));
      h4.w = bfbits(r.w); l4.w = bfbits(r.w - hi_f(h4.w));
      *reinterpret_cast<ushort4*>(&oph[(size_t)wid * 64 + lane * 4]) = h4;
      *reinterpret_cast<ushort4*>(&opl[(size_t)wid * 64 + lane * 4]) = l4;
    }
  }
}

// ---------------------------------------------------------------- SAGE agg
__global__ __launch_bounds__(256) void k_agg(
    const int* __restrict__ off, const int* __restrict__ csr_src,
    const float* __restrict__ h3, float* __restrict__ agg) {
  int wid = (blockIdx.x << 2) + (threadIdx.x >> 6);
  int lane = threadIdx.x & 63;
  if (wid >= NN) return;
  int beg = off[wid], end = off[wid + 1];
  float acc = 0.f;
  int e = beg;
  for (; e + 4 <= end; e += 4) {
    int s0 = csr_src[e + 0], s1 = csr_src[e + 1];
    int s2 = csr_src[e + 2], s3 = csr_src[e + 3];
    float v0 = h3[(size_t)s0 * 64 + lane];
    float v1 = h3[(size_t)s1 * 64 + lane];
    float v2 = h3[(size_t)s2 * 64 + lane];
    float v3 = h3[(size_t)s3 * 64 + lane];
    acc += (v0 + v1) + (v2 + v3);
  }
  for (; e < end; ++e) acc += h3[(size_t)csr_src[e] * 64 + lane];
  agg[(size_t)wid * 64 + lane] = acc / fmaxf((float)(end - beg), 1.f);
}

// ---------------------------------------------------------------- SAGE GEMM
__global__ __launch_bounds__(256) void k_sage_mm(
    const float* __restrict__ agg, const float* __restrict__ h3,
    const float* __restrict__ Wl, const float* __restrict__ Wr,
    const float* __restrict__ bias, float* __restrict__ out) {
  __shared__ float WlS[4096];
  __shared__ float WrS[4096];
  __shared__ float Ag[2048];
  __shared__ float Hr[2048];
  int t = threadIdx.x;
  for (int i = t; i < 4096; i += 256) { WlS[i] = Wl[i]; WrS[i] = Wr[i]; }
  int ct = t & 15, rg = t >> 4;
  float4 bv = reinterpret_cast<const float4*>(bias)[ct];
  for (int r0 = blockIdx.x * 32; r0 < NN; r0 += gridDim.x * 32) {
    for (int i = t; i < 2048; i += 256) {
      int n = r0 + (i >> 6);
      float va = 0.f, vh = 0.f;
      if (n < NN) {
        va = agg[(size_t)n * 64 + (i & 63)];
        vh = h3[(size_t)n * 64 + (i & 63)];
      }
      Ag[i] = va; Hr[i] = vh;
    }
    __syncthreads();
    float4 c0 = {0.f, 0.f, 0.f, 0.f}, c1 = c0;
    const float* a0 = &Ag[(rg * 2 + 0) * 64];
    const float* a1 = &Ag[(rg * 2 + 1) * 64];
    const float* h0 = &Hr[(rg * 2 + 0) * 64];
    const float* h1 = &Hr[(rg * 2 + 1) * 64];
    #pragma unroll 4
    for (int k = 0; k < 64; k += 4) {
      float4 wl0 = *reinterpret_cast<const float4*>(&WlS[(k + 0) * 64 + ct * 4]);
      float4 wl1 = *reinterpret_cast<const float4*>(&WlS[(k + 1) * 64 + ct * 4]);
      float4 wl2 = *reinterpret_cast<const float4*>(&WlS[(k + 2) * 64 + ct * 4]);
      float4 wl3 = *reinterpret_cast<const float4*>(&WlS[(k + 3) * 64 + ct * 4]);
      float4 wr0 = *reinterpret_cast<const float4*>(&WrS[(k + 0) * 64 + ct * 4]);
      float4 wr1 = *reinterpret_cast<const float4*>(&WrS[(k + 1) * 64 + ct * 4]);
      float4 wr2 = *reinterpret_cast<const float4*>(&WrS[(k + 2) * 64 + ct * 4]);
      float4 wr3 = *reinterpret_cast<const float4*>(&WrS[(k + 3) * 64 + ct * 4]);
      float4 aa0 = *reinterpret_cast<const float4*>(&a0[k]);
      float4 aa1 = *reinterpret_cast<const float4*>(&a1[k]);
      float4 hh0 = *reinterpret_cast<const float4*>(&h0[k]);
      float4 hh1 = *reinterpret_cast<const float4*>(&h1[k]);
      c0 = f4fma(aa0.x, wl0, c0); c0 = f4fma(aa0.y, wl1, c0);
      c0 = f4fma(aa0.z, wl2, c0); c0 = f4fma(aa0.w, wl3, c0);
      c0 = f4fma(hh0.x, wr0, c0); c0 = f4fma(hh0.y, wr1, c0);
      c0 = f4fma(hh0.z, wr2, c0); c0 = f4fma(hh0.w, wr3, c0);
      c1 = f4fma(aa1.x, wl0, c1); c1 = f4fma(aa1.y, wl1, c1);
      c1 = f4fma(aa1.z, wl2, c1); c1 = f4fma(aa1.w, wl3, c1);
      c1 = f4fma(hh1.x, wr0, c1); c1 = f4fma(hh1.y, wr1, c1);
      c1 = f4fma(hh1.z, wr2, c1); c1 = f4fma(hh1.w, wr3, c1);
    }
    int n0 = r0 + rg * 2;
    if (n0 + 0 < NN) {
      float4 r;
      r.x = eluf(c0.x + bv.x); r.y = eluf(c0.y + bv.y);
      r.z = eluf(c0.z + bv.z); r.w = eluf(c0.w + bv.w);
      *reinterpret_cast<float4*>(&out[(size_t)(n0 + 0) * 64 + ct * 4]) = r;
    }
    if (n0 + 1 < NN) {
      float4 r;
      r.x = eluf(c1.x + bv.x); r.y = eluf(c1.y + bv.y);
      r.z = eluf(c1.z + bv.z); r.w = eluf(c1.w + bv.w);
      *reinterpret_cast<float4*>(&out[(size_t)(n0 + 1) * 64 + ct * 4]) = r;
    }
    __syncthreads();
  }
}

// ---------------------------------------------------------------- pooling
__device__ __forceinline__ int lowerb(const int* __restrict__ a, int n, int key) {
  int lo = 0, hi = n;
  while (lo < hi) { int mid = (lo + hi) >> 1; if (a[mid] < key) lo = mid + 1; else hi = mid; }
  return lo;
}

__global__ __launch_bounds__(256) void k_pool(const float* __restrict__ hs,
                                              const int* __restrict__ batch,
                                              float* __restrict__ g) {
  int b = blockIdx.x;
  int lo = lowerb(batch, NN, b), hi = lowerb(batch, NN, b + 1);
  int t = threadIdx.x, lane = t & 63, w = t >> 6;
  float acc = 0.f;
  for (int n = lo + w; n < hi; n += 4) acc += hs[(size_t)n * 64 + lane];
  __shared__ float red[4][64];
  red[w][lane] = acc;
  __syncthreads();
  if (w == 0) {
    float v = red[0][lane] + red[1][lane] + red[2][lane] + red[3][lane];
    g[b * 64 + lane] = v / fmaxf((float)(hi - lo), 1.f);
  }
}

// ---------------------------------------------------------------- MLP head
__global__ __launch_bounds__(256) void k_head(
    const float* __restrict__ g, const float* __restrict__ l1W,
    const float* __restrict__ l1b, const float* __restrict__ l2W,
    const float* __restrict__ l2b, const float* __restrict__ telW,
    const float* __restrict__ telb, const float* __restrict__ compW,
    const float* __restrict__ compb, const float* __restrict__ pchW,
    const float* __restrict__ pchb, float* __restrict__ out) {
  __shared__ float gS[4096];
  __shared__ float WS[4096];
  __shared__ float hS[4096];
  int t = threadIdx.x;
  for (int i = t; i < 4096; i += 256) { gS[i] = g[i]; WS[i] = l1W[i]; }
  __syncthreads();
  for (int i = t; i < 4096; i += 256) {
    int r = i >> 6, j = i & 63;
    float s = 0.f;
    for (int k = 0; k < 64; ++k) s += gS[r * 64 + k] * WS[k * 64 + j];
    hS[i] = eluf(s + l1b[j]);
  }
  __syncthreads();
  for (int i = t; i < 4096; i += 256) WS[i] = l2W[i];
  __syncthreads();
  for (int i = t; i < 4096; i += 256) {
    int r = i >> 6, j = i & 63;
    float s = 0.f;
    for (int k = 0; k < 64; ++k) s += hS[r * 64 + k] * WS[k * 64 + j];
    gS[i] = s + l2b[j];
  }
  __syncthreads();
  if (t < 192) {
    int head = t >> 6, r = t & 63;
    const float* Wv = head == 0 ? telW : (head == 1 ? compW : pchW);
    float bb = head == 0 ? telb[0] : (head == 1 ? compb[0] : pchb[0]);
    float s = 0.f;
    for (int k = 0; k < 64; ++k) s += gS[r * 64 + k] * Wv[k];
    out[t] = s + bb;
  }
}

// ---------------------------------------------------------------- launch
extern "C" void kernel_launch(void* const* d_in, const int* in_sizes, int n_in,
                              void* d_out, int out_size, void* d_ws, size_t ws_size,
                              hipStream_t stream) {
  const float* x     = (const float*)d_in[0];
  const int*   eidx  = (const int*)d_in[1];
  const float* eattr = (const float*)d_in[2];
  const int*   batch = (const int*)d_in[3];
  const int*   ntype = (const int*)d_in[4];
  const float* nemb  = (const float*)d_in[5];
  const float* edgeW = (const float*)d_in[6];
  const float* edgeB = (const float*)d_in[7];
  const float* W1    = (const float*)d_in[8];
  const float* atts1 = (const float*)d_in[9];
  const float* attd1 = (const float*)d_in[10];
  const float* We1   = (const float*)d_in[11];
  const float* atte1 = (const float*)d_in[12];
  const float* b1    = (const float*)d_in[13];
  const float* W2    = (const float*)d_in[14];
  const float* atts2 = (const float*)d_in[15];
  const float* attd2 = (const float*)d_in[16];
  const float* We2   = (const float*)d_in[17];
  const float* atte2 = (const float*)d_in[18];
  const float* b2    = (const float*)d_in[19];
  const float* sageWl = (const float*)d_in[20];
  const float* sageWr = (const float*)d_in[21];
  const float* sageB  = (const float*)d_in[22];
  const float* l1W = (const float*)d_in[23];
  const float* l1b = (const float*)d_in[24];
  const float* l2W = (const float*)d_in[25];
  const float* l2b = (const float*)d_in[26];
  const float* telW  = (const float*)d_in[27];
  const float* telb  = (const float*)d_in[28];
  const float* compW = (const float*)d_in[29];
  const float* compb = (const float*)d_in[30];
  const float* pchW  = (const float*)d_in[31];
  const float* pchb  = (const float*)d_in[32];

  char* wp = (char*)d_ws;
  auto alloc = [&](size_t bytes) -> char* {
    char* p = wp;
    wp += (bytes + 255) & ~(size_t)255;
    return p;
  };
  float*  pq      = (float*)alloc(16 * 4);
  int*    cnt     = (int*)alloc((size_t)NN * 4);
  int*    off     = (int*)alloc(((size_t)NN + 1) * 4);
  int*    csr_src = (int*)alloc((size_t)NE * 4);
  float*  csr_ea  = (float*)alloc((size_t)NE * 4);
  float*  as_     = (float*)alloc((size_t)NN * 16);
  float*  ad_     = (float*)alloc((size_t)NN * 16);
  bf16*   hmat    = (bf16*)alloc((size_t)NN * 256 * 2);
  float*  nodeB   = (float*)alloc((size_t)NN * 64 * 4);
  float*  aggbuf  = (float*)alloc((size_t)NN * 64 * 4);
  unsigned short* B1h = (unsigned short*)alloc(256 * 96 * 2);
  unsigned short* B1l = (unsigned short*)alloc(256 * 96 * 2);
  unsigned short* B2h = (unsigned short*)alloc(256 * 64 * 2);
  unsigned short* B2l = (unsigned short*)alloc(256 * 64 * 2);
  // overlaid region R: A1 planes (19.2MB) -> A2 planes (12.8MB) -> sage out
  char* R = alloc((size_t)NN * 96 * 2 * 2);
  unsigned short* A1h = (unsigned short*)R;
  unsigned short* A1l = A1h + (size_t)NN * 96;
  unsigned short* A2h = (unsigned short*)R;
  unsigned short* A2l = A2h + (size_t)NN * 64;
  float* sageout = (float*)R;
  float* gbuf = (float*)alloc(64 * 64 * 4);

  const int* srcI = eidx;
  const int* dstI = eidx + NE;

  hipMemsetAsync(cnt, 0, (size_t)NN * 4, stream);
  k_pq<<<1, 256, 0, stream>>>(We1, atte1, We2, atte2, edgeW, edgeB, pq);
  k_hist<<<(NE + 255) / 256, 256, 0, stream>>>(dstI, cnt);
  k_scan<<<1, 1024, 0, stream>>>(cnt, off);
  hipMemsetAsync(cnt, 0, (size_t)NN * 4, stream);
  k_scatter<<<(NE + 255) / 256, 256, 0, stream>>>(srcI, dstI, eattr, off, cnt,
                                                  csr_src, csr_ea);
  k_splitW<<<96, 256, 0, stream>>>(W1, W2, B1h, B1l, B2h, B2l);
  k_splitA<<<2048, 256, 0, stream>>>(x, ntype, nemb, A1h, A1l);
  // GAT layer 1
  k_mm_mfma<96><<<(NN + 63) / 64, 256, 0, stream>>>(
      A1h, A1l, B1h, B1l, atts1, attd1, hmat, as_, ad_);
  k_gat<<<NN / 4, 256, 0, stream>>>(off, csr_src, csr_ea, as_, ad_, pq, 0,
                                    hmat, b1, nullptr, A2h, A2l);
  // GAT layer 2
  k_mm_mfma<64><<<(NN + 63) / 64, 256, 0, stream>>>(
      A2h, A2l, B2h, B2l, atts2, attd2, hmat, as_, ad_);
  k_gat<<<NN / 4, 256, 0, stream>>>(off, csr_src, csr_ea, as_, ad_, pq, 8,
                                    hmat, b2, nodeB, nullptr, nullptr);
  // SAGE + pool + head
  k_agg<<<NN / 4, 256, 0, stream>>>(off, csr_src, nodeB, aggbuf);
  k_sage_mm<<<1024, 256, 0, stream>>>(aggbuf, nodeB, sageWl, sageWr, sageB,
                                      sageout);
  k_pool<<<NBATCH, 256, 0, stream>>>(sageout, batch, gbuf);
  k_head<<<1, 256, 0, stream>>>(gbuf, l1W, l1b, l2W, l2b, telW, telb, compW,
                                compb, pchW, pchb, (float*)d_out);
}

// Round 8
// 468.207 us; speedup vs baseline: 1.7046x; 1.0472x over previous
//
#include <hip/hip_runtime.h>
#include <hip/hip_bf16.h>

// EnhancedTelomeraseGNN on MI355X — round 8.
// f32 in/out. GEMMs on MFMA (16x16x32 bf16, split-bf16 hi/lo, 3 mfmas/K-step
// -> f32-equivalent). a_e = ea*p[h]+q[h] collapse. hmat bf16 messages.
// Round-8: k_pool rebuilt as wave-per-32-node-chunk with atomic segment
// flush (was 64 blocks = 1 wave/CU latency chain, 57us @ 2.4% occupancy);
// normalization folded into k_head via binary-search counts.
//
// Workspace (~76 MB, overlaid): pq | cnt | off | csr_src | csr_ea | as | ad |
// hmat bf16[N,256] | nodeB f32[N,64] | agg f32[N,64] | B-planes | R(19.2MB):
// A1 planes -> A2 planes -> sage-out f32 | gbuf.

#define NN 50000
#define NE 400000
#define FIN 32
#define NBATCH 64

typedef __hip_bfloat16 bf16;
typedef short bf16x8 __attribute__((ext_vector_type(8)));
typedef float f32x4 __attribute__((ext_vector_type(4)));

__device__ __forceinline__ float b2f(bf16 v) { return __bfloat162float(v); }
__device__ __forceinline__ float lrelu(float x) { return x > 0.f ? x : 0.2f * x; }
__device__ __forceinline__ float eluf(float x) { return x > 0.f ? x : (expf(x) - 1.f); }

__device__ __forceinline__ float4 f4fma(float s, float4 w, float4 c) {
  c.x = fmaf(s, w.x, c.x); c.y = fmaf(s, w.y, c.y);
  c.z = fmaf(s, w.z, c.z); c.w = fmaf(s, w.w, c.w);
  return c;
}

__device__ __forceinline__ float4 upk4(uint2 u) {
  float4 f;
  f.x = __uint_as_float(u.x << 16);
  f.y = __uint_as_float(u.x & 0xffff0000u);
  f.z = __uint_as_float(u.y << 16);
  f.w = __uint_as_float(u.y & 0xffff0000u);
  return f;
}

__device__ __forceinline__ unsigned short bfbits(float f) {
  bf16 b = __float2bfloat16(f);
  unsigned short u;
  __builtin_memcpy(&u, &b, 2);
  return u;
}
__device__ __forceinline__ float hi_f(unsigned short u) {
  return __uint_as_float((unsigned int)u << 16);
}

// ---------------------------------------------------------------- p/q scalars
__global__ __launch_bounds__(256) void k_pq(
    const float* __restrict__ We1, const float* __restrict__ atte1,
    const float* __restrict__ We2, const float* __restrict__ atte2,
    const float* __restrict__ edgeW, const float* __restrict__ edgeB,
    float* __restrict__ pq) {
  int t = threadIdx.x, h = t >> 6, c = t & 63;
  float sW1 = 0.f, sB1 = 0.f, sW2 = 0.f, sB2 = 0.f;
  for (int j = 0; j < 64; ++j) {
    float w = edgeW[j], b = edgeB[j];
    float we1 = We1[j * 256 + h * 64 + c];
    float we2 = We2[j * 256 + h * 64 + c];
    sW1 += w * we1; sB1 += b * we1;
    sW2 += w * we2; sB2 += b * we2;
  }
  float a1 = atte1[h * 64 + c], a2 = atte2[h * 64 + c];
  float p1 = sW1 * a1, q1 = sB1 * a1, p2 = sW2 * a2, q2 = sB2 * a2;
  for (int o = 32; o; o >>= 1) {
    p1 += __shfl_xor(p1, o); q1 += __shfl_xor(q1, o);
    p2 += __shfl_xor(p2, o); q2 += __shfl_xor(q2, o);
  }
  if (c == 0) { pq[h] = p1; pq[4 + h] = q1; pq[8 + h] = p2; pq[12 + h] = q2; }
}

// ---------------------------------------------------------------- CSR build
__global__ void k_hist(const int* __restrict__ dst, int* __restrict__ cnt) {
  int e = blockIdx.x * 256 + threadIdx.x;
  if (e < NE) atomicAdd(&cnt[dst[e]], 1);
}

__global__ __launch_bounds__(1024) void k_scan(const int* __restrict__ cnt,
                                               int* __restrict__ off) {
  __shared__ int wsum[16];
  __shared__ int carry;
  int t = threadIdx.x, lane = t & 63, w = t >> 6;
  if (t == 0) { carry = 0; off[0] = 0; }
  __syncthreads();
  for (int base = 0; base < NN; base += 1024) {
    int idx = base + t;
    int v = (idx < NN) ? cnt[idx] : 0;
    int s = v;
    for (int o = 1; o < 64; o <<= 1) { int u = __shfl_up(s, o); if (lane >= o) s += u; }
    if (lane == 63) wsum[w] = s;
    __syncthreads();
    if (t < 16) {
      int ws = wsum[t];
      for (int o = 1; o < 16; o <<= 1) { int u = __shfl_up(ws, o); if (t >= o) ws += u; }
      wsum[t] = ws;
    }
    __syncthreads();
    int add = carry + (w ? wsum[w - 1] : 0);
    if (idx < NN) off[idx + 1] = add + s;
    __syncthreads();
    if (t == 0) carry += wsum[15];
    __syncthreads();
  }
}

__global__ void k_scatter(const int* __restrict__ src, const int* __restrict__ dst,
                          const float* __restrict__ ea, const int* __restrict__ off,
                          int* __restrict__ cur, int* __restrict__ csr_src,
                          float* __restrict__ csr_ea) {
  int e = blockIdx.x * 256 + threadIdx.x;
  if (e >= NE) return;
  int d = dst[e];
  int slot = off[d] + atomicAdd(&cur[d], 1);
  csr_src[slot] = src[e];
  csr_ea[slot] = ea[e];
}

// ---------------------------------------------------------------- split prep
__global__ __launch_bounds__(256) void k_splitA(
    const float* __restrict__ x, const int* __restrict__ ntype,
    const float* __restrict__ emb, unsigned short* __restrict__ Ah,
    unsigned short* __restrict__ Al) {
  const int total = NN * 96;
  for (int i = blockIdx.x * 256 + threadIdx.x; i < total; i += gridDim.x * 256) {
    int n = i / 96, k = i - n * 96;
    float v = (k < FIN) ? x[n * FIN + k] : emb[ntype[n] * 64 + (k - FIN)];
    unsigned short h = bfbits(v);
    Ah[i] = h;
    Al[i] = bfbits(v - hi_f(h));
  }
}

__global__ __launch_bounds__(256) void k_splitW(
    const float* __restrict__ W1, const float* __restrict__ W2,
    unsigned short* __restrict__ B1h, unsigned short* __restrict__ B1l,
    unsigned short* __restrict__ B2h, unsigned short* __restrict__ B2l) {
  int t = blockIdx.x * 256 + threadIdx.x;
  if (t < 256 * 96) {
    int n = t / 96, k = t - n * 96;
    float v = W1[k * 256 + n];
    unsigned short h = bfbits(v);
    B1h[t] = h; B1l[t] = bfbits(v - hi_f(h));
  }
  if (t < 256 * 64) {
    int n = t >> 6, k = t & 63;
    float v = W2[k * 256 + n];
    unsigned short h = bfbits(v);
    B2h[t] = h; B2l[t] = bfbits(v - hi_f(h));
  }
}

// ---------------------------------------------------------------- MFMA GEMM
template <int K>
__global__ __launch_bounds__(256) void k_mm_mfma(
    const unsigned short* __restrict__ Ah, const unsigned short* __restrict__ Al,
    const unsigned short* __restrict__ Bh, const unsigned short* __restrict__ Bl,
    const float* __restrict__ atts, const float* __restrict__ attd,
    bf16* __restrict__ hmat, float* __restrict__ as_, float* __restrict__ ad_) {
  int m0 = blockIdx.x * 64;
  int w = threadIdx.x >> 6;     // wave = head
  int lane = threadIdx.x & 63;
  int lr = lane & 15;
  int lc = lane >> 4;
  float attsv[4], attdv[4];
  #pragma unroll
  for (int nt = 0; nt < 4; ++nt) {
    attsv[nt] = atts[w * 64 + nt * 16 + lr];
    attdv[nt] = attd[w * 64 + nt * 16 + lr];
  }
  f32x4 acc[4][4] = {};
  #pragma unroll
  for (int ks = 0; ks < K; ks += 32) {
    int koff = ks + lc * 8;
    bf16x8 ah[4], al[4], bh[4], bl[4];
    #pragma unroll
    for (int mt = 0; mt < 4; ++mt) {
      int m = m0 + mt * 16 + lr;
      if (m > NN - 1) m = NN - 1;
      ah[mt] = *reinterpret_cast<const bf16x8*>(&Ah[(size_t)m * K + koff]);
      al[mt] = *reinterpret_cast<const bf16x8*>(&Al[(size_t)m * K + koff]);
    }
    #pragma unroll
    for (int nt = 0; nt < 4; ++nt) {
      int n = w * 64 + nt * 16 + lr;
      bh[nt] = *reinterpret_cast<const bf16x8*>(&Bh[(size_t)n * K + koff]);
      bl[nt] = *reinterpret_cast<const bf16x8*>(&Bl[(size_t)n * K + koff]);
    }
    #pragma unroll
    for (int mt = 0; mt < 4; ++mt) {
      #pragma unroll
      for (int nt = 0; nt < 4; ++nt) {
        acc[mt][nt] = __builtin_amdgcn_mfma_f32_16x16x32_bf16(ah[mt], bh[nt], acc[mt][nt], 0, 0, 0);
        acc[mt][nt] = __builtin_amdgcn_mfma_f32_16x16x32_bf16(al[mt], bh[nt], acc[mt][nt], 0, 0, 0);
        acc[mt][nt] = __builtin_amdgcn_mfma_f32_16x16x32_bf16(ah[mt], bl[nt], acc[mt][nt], 0, 0, 0);
      }
    }
  }
  #pragma unroll
  for (int mt = 0; mt < 4; ++mt) {
    #pragma unroll
    for (int reg = 0; reg < 4; ++reg) {
      int row = m0 + mt * 16 + lc * 4 + reg;
      float sS = 0.f, sD = 0.f;
      #pragma unroll
      for (int nt = 0; nt < 4; ++nt) {
        float v = acc[mt][nt][reg];
        sS += v * attsv[nt];
        sD += v * attdv[nt];
      }
      for (int o = 1; o < 16; o <<= 1) {
        sS += __shfl_xor(sS, o);
        sD += __shfl_xor(sD, o);
      }
      if (row < NN) {
        #pragma unroll
        for (int nt = 0; nt < 4; ++nt)
          hmat[(size_t)row * 256 + w * 64 + nt * 16 + lr] =
              __float2bfloat16(acc[mt][nt][reg]);
        if (lr == 0) { as_[row * 4 + w] = sS; ad_[row * 4 + w] = sD; }
      }
    }
  }
}

// ---------------------------------------------------------------- GAT
__global__ __launch_bounds__(256) void k_gat(
    const int* __restrict__ off, const int* __restrict__ csr_src,
    const float* __restrict__ csr_ea, const float* __restrict__ as_,
    const float* __restrict__ ad_, const float* __restrict__ pq, int pqo,
    const bf16* __restrict__ hmat, const float* __restrict__ bias,
    float* __restrict__ outf, unsigned short* __restrict__ oph,
    unsigned short* __restrict__ opl) {
  __shared__ float wlds[4][256];
  int wv = threadIdx.x >> 6;
  int wid = (blockIdx.x << 2) + wv;
  int lane = threadIdx.x & 63;
  if (wid >= NN) return;
  int beg = off[wid], end = off[wid + 1];
  int deg = end - beg;
  int hsel = lane >> 4;
  float4 D = reinterpret_cast<const float4*>(ad_)[wid];
  float p0 = pq[pqo + 0], p1 = pq[pqo + 1], p2 = pq[pqo + 2], p3 = pq[pqo + 3];
  float q0 = pq[pqo + 4], q1 = pq[pqo + 5], q2 = pq[pqo + 6], q3 = pq[pqo + 7];
  float4 acc = {0.f, 0.f, 0.f, 0.f};

  if (deg <= 64) {
    bool valid = lane < deg;
    float lx = -INFINITY, ly = -INFINITY, lz = -INFINITY, lw = -INFINITY;
    if (valid) {
      int s = csr_src[beg + lane];
      float ea = csr_ea[beg + lane];
      float4 A = reinterpret_cast<const float4*>(as_)[s];
      lx = lrelu(A.x + D.x + ea * p0 + q0);
      ly = lrelu(A.y + D.y + ea * p1 + q1);
      lz = lrelu(A.z + D.z + ea * p2 + q2);
      lw = lrelu(A.w + D.w + ea * p3 + q3);
    }
    float m0 = lx, m1 = ly, m2 = lz, m3 = lw;
    for (int o = 32; o; o >>= 1) {
      m0 = fmaxf(m0, __shfl_xor(m0, o));
      m1 = fmaxf(m1, __shfl_xor(m1, o));
      m2 = fmaxf(m2, __shfl_xor(m2, o));
      m3 = fmaxf(m3, __shfl_xor(m3, o));
    }
    float w0 = valid ? __expf(lx - m0) : 0.f;
    float w1 = valid ? __expf(ly - m1) : 0.f;
    float w2 = valid ? __expf(lz - m2) : 0.f;
    float w3 = valid ? __expf(lw - m3) : 0.f;
    float s0 = w0, s1 = w1, s2 = w2, s3 = w3;
    for (int o = 32; o; o >>= 1) {
      s0 += __shfl_xor(s0, o); s1 += __shfl_xor(s1, o);
      s2 += __shfl_xor(s2, o); s3 += __shfl_xor(s3, o);
    }
    float4 wv4;
    wv4.x = w0 / (s0 + 1e-16f);
    wv4.y = w1 / (s1 + 1e-16f);
    wv4.z = w2 / (s2 + 1e-16f);
    wv4.w = w3 / (s3 + 1e-16f);
    reinterpret_cast<float4*>(&wlds[wv][0])[lane] = wv4;
    const float* wp = &wlds[wv][0];
    int j = 0;
    for (; j + 4 <= deg; j += 4) {
      int sA = csr_src[beg + j + 0];
      int sB = csr_src[beg + j + 1];
      int sC = csr_src[beg + j + 2];
      int sD = csr_src[beg + j + 3];
      float wA = wp[4 * (j + 0) + hsel];
      float wB = wp[4 * (j + 1) + hsel];
      float wC = wp[4 * (j + 2) + hsel];
      float wD = wp[4 * (j + 3) + hsel];
      uint2 uA = *reinterpret_cast<const uint2*>(&hmat[(size_t)sA * 256 + 4 * lane]);
      uint2 uB = *reinterpret_cast<const uint2*>(&hmat[(size_t)sB * 256 + 4 * lane]);
      uint2 uC = *reinterpret_cast<const uint2*>(&hmat[(size_t)sC * 256 + 4 * lane]);
      uint2 uD = *reinterpret_cast<const uint2*>(&hmat[(size_t)sD * 256 + 4 * lane]);
      acc = f4fma(wA, upk4(uA), acc);
      acc = f4fma(wB, upk4(uB), acc);
      acc = f4fma(wC, upk4(uC), acc);
      acc = f4fma(wD, upk4(uD), acc);
    }
    for (; j < deg; ++j) {
      int s = csr_src[beg + j];
      float w = wp[4 * j + hsel];
      uint2 u = *reinterpret_cast<const uint2*>(&hmat[(size_t)s * 256 + 4 * lane]);
      acc = f4fma(w, upk4(u), acc);
    }
  } else {
    float m0 = -INFINITY, m1 = -INFINITY, m2 = -INFINITY, m3 = -INFINITY;
    float s0 = 0.f, s1 = 0.f, s2 = 0.f, s3 = 0.f;
    for (int e = beg + lane; e < end; e += 64) {
      int s = csr_src[e];
      float ea = csr_ea[e];
      float4 A = reinterpret_cast<const float4*>(as_)[s];
      float lx = lrelu(A.x + D.x + ea * p0 + q0);
      float ly = lrelu(A.y + D.y + ea * p1 + q1);
      float lz = lrelu(A.z + D.z + ea * p2 + q2);
      float lw = lrelu(A.w + D.w + ea * p3 + q3);
      float nm;
      nm = fmaxf(m0, lx); s0 = s0 * __expf(m0 - nm) + __expf(lx - nm); m0 = nm;
      nm = fmaxf(m1, ly); s1 = s1 * __expf(m1 - nm) + __expf(ly - nm); m1 = nm;
      nm = fmaxf(m2, lz); s2 = s2 * __expf(m2 - nm) + __expf(lz - nm); m2 = nm;
      nm = fmaxf(m3, lw); s3 = s3 * __expf(m3 - nm) + __expf(lw - nm); m3 = nm;
    }
    for (int o = 32; o; o >>= 1) {
      float om, os, nm;
      om = __shfl_xor(m0, o); os = __shfl_xor(s0, o); nm = fmaxf(m0, om);
      s0 = s0 * __expf(fmaxf(m0 - nm, -80.f)) + os * __expf(fmaxf(om - nm, -80.f)); m0 = nm;
      om = __shfl_xor(m1, o); os = __shfl_xor(s1, o); nm = fmaxf(m1, om);
      s1 = s1 * __expf(fmaxf(m1 - nm, -80.f)) + os * __expf(fmaxf(om - nm, -80.f)); m1 = nm;
      om = __shfl_xor(m2, o); os = __shfl_xor(s2, o); nm = fmaxf(m2, om);
      s2 = s2 * __expf(fmaxf(m2 - nm, -80.f)) + os * __expf(fmaxf(om - nm, -80.f)); m2 = nm;
      om = __shfl_xor(m3, o); os = __shfl_xor(s3, o); nm = fmaxf(m3, om);
      s3 = s3 * __expf(fmaxf(m3 - nm, -80.f)) + os * __expf(fmaxf(om - nm, -80.f)); m3 = nm;
    }
    float i0 = 1.f / (s0 + 1e-16f), i1 = 1.f / (s1 + 1e-16f);
    float i2 = 1.f / (s2 + 1e-16f), i3 = 1.f / (s3 + 1e-16f);
    float Dh = hsel == 0 ? D.x : hsel == 1 ? D.y : hsel == 2 ? D.z : D.w;
    float ph = hsel == 0 ? p0 : hsel == 1 ? p1 : hsel == 2 ? p2 : p3;
    float qh = hsel == 0 ? q0 : hsel == 1 ? q1 : hsel == 2 ? q2 : q3;
    float mh = hsel == 0 ? m0 : hsel == 1 ? m1 : hsel == 2 ? m2 : m3;
    float ih = hsel == 0 ? i0 : hsel == 1 ? i1 : hsel == 2 ? i2 : i3;
    for (int j = beg; j < end; ++j) {
      int s = csr_src[j];
      float ea = csr_ea[j];
      float4 A = reinterpret_cast<const float4*>(as_)[s];
      float Ah = hsel == 0 ? A.x : hsel == 1 ? A.y : hsel == 2 ? A.z : A.w;
      float l = lrelu(Ah + Dh + ea * ph + qh);
      float w = __expf(l - mh) * ih;
      uint2 u = *reinterpret_cast<const uint2*>(&hmat[(size_t)s * 256 + 4 * lane]);
      acc = f4fma(w, upk4(u), acc);
    }
  }
  acc.x += __shfl_xor(acc.x, 16); acc.y += __shfl_xor(acc.y, 16);
  acc.z += __shfl_xor(acc.z, 16); acc.w += __shfl_xor(acc.w, 16);
  acc.x += __shfl_xor(acc.x, 32); acc.y += __shfl_xor(acc.y, 32);
  acc.z += __shfl_xor(acc.z, 32); acc.w += __shfl_xor(acc.w, 32);
  if (lane < 16) {
    float4 bv = reinterpret_cast<const float4*>(bias)[lane];
    float4 r;
    r.x = eluf(0.25f * acc.x + bv.x);
    r.y = eluf(0.25f * acc.y + bv.y);
    r.z = eluf(0.25f * acc.z + bv.z);
    r.w = eluf(0.25f * acc.w + bv.w);
    if (outf) reinterpret_cast<float4*>(&outf[(size_t)wid * 64])[lane] = r;
    if (oph) {
      ushort4 h4, l4;
      h4.x = bfbits(r.x); l4.x = bfbits(r.x - hi_f(h4.x));
      h4.y = bfbits(r.y); l4.y = bfbits(r.y - hi_f(h4.y));
      h4.z = bfbits(r.z); l4.z = bfbits(r.z - hi_f(h4.z));
      h4.w = bfbits(r.w); l4.w = bfbits(r.w - hi_f(h4.w));
      *reinterpret_cast<ushort4*>(&oph[(size_t)wid * 64 + lane * 4]) = h4;
      *reinterpret_cast<ushort4*>(&opl[(size_t)wid * 64 + lane * 4]) = l4;
    }
  }
}

// ---------------------------------------------------------------- SAGE agg
__global__ __launch_bounds__(256) void k_agg(
    const int* __restrict__ off, const int* __restrict__ csr_src,
    const float* __restrict__ h3, float* __restrict__ agg) {
  int wid = (blockIdx.x << 2) + (threadIdx.x >> 6);
  int lane = threadIdx.x & 63;
  if (wid >= NN) return;
  int beg = off[wid], end = off[wid + 1];
  float acc = 0.f;
  int e = beg;
  for (; e + 4 <= end; e += 4) {
    int s0 = csr_src[e + 0], s1 = csr_src[e + 1];
    int s2 = csr_src[e + 2], s3 = csr_src[e + 3];
    float v0 = h3[(size_t)s0 * 64 + lane];
    float v1 = h3[(size_t)s1 * 64 + lane];
    float v2 = h3[(size_t)s2 * 64 + lane];
    float v3 = h3[(size_t)s3 * 64 + lane];
    acc += (v0 + v1) + (v2 + v3);
  }
  for (; e < end; ++e) acc += h3[(size_t)csr_src[e] * 64 + lane];
  agg[(size_t)wid * 64 + lane] = acc / fmaxf((float)(end - beg), 1.f);
}

// ---------------------------------------------------------------- SAGE GEMM
__global__ __launch_bounds__(256) void k_sage_mm(
    const float* __restrict__ agg, const float* __restrict__ h3,
    const float* __restrict__ Wl, const float* __restrict__ Wr,
    const float* __restrict__ bias, float* __restrict__ out) {
  __shared__ float WlS[4096];
  __shared__ float WrS[4096];
  __shared__ float Ag[2048];
  __shared__ float Hr[2048];
  int t = threadIdx.x;
  for (int i = t; i < 4096; i += 256) { WlS[i] = Wl[i]; WrS[i] = Wr[i]; }
  int ct = t & 15, rg = t >> 4;
  float4 bv = reinterpret_cast<const float4*>(bias)[ct];
  for (int r0 = blockIdx.x * 32; r0 < NN; r0 += gridDim.x * 32) {
    for (int i = t; i < 2048; i += 256) {
      int n = r0 + (i >> 6);
      float va = 0.f, vh = 0.f;
      if (n < NN) {
        va = agg[(size_t)n * 64 + (i & 63)];
        vh = h3[(size_t)n * 64 + (i & 63)];
      }
      Ag[i] = va; Hr[i] = vh;
    }
    __syncthreads();
    float4 c0 = {0.f, 0.f, 0.f, 0.f}, c1 = c0;
    const float* a0 = &Ag[(rg * 2 + 0) * 64];
    const float* a1 = &Ag[(rg * 2 + 1) * 64];
    const float* h0 = &Hr[(rg * 2 + 0) * 64];
    const float* h1 = &Hr[(rg * 2 + 1) * 64];
    #pragma unroll 4
    for (int k = 0; k < 64; k += 4) {
      float4 wl0 = *reinterpret_cast<const float4*>(&WlS[(k + 0) * 64 + ct * 4]);
      float4 wl1 = *reinterpret_cast<const float4*>(&WlS[(k + 1) * 64 + ct * 4]);
      float4 wl2 = *reinterpret_cast<const float4*>(&WlS[(k + 2) * 64 + ct * 4]);
      float4 wl3 = *reinterpret_cast<const float4*>(&WlS[(k + 3) * 64 + ct * 4]);
      float4 wr0 = *reinterpret_cast<const float4*>(&WrS[(k + 0) * 64 + ct * 4]);
      float4 wr1 = *reinterpret_cast<const float4*>(&WrS[(k + 1) * 64 + ct * 4]);
      float4 wr2 = *reinterpret_cast<const float4*>(&WrS[(k + 2) * 64 + ct * 4]);
      float4 wr3 = *reinterpret_cast<const float4*>(&WrS[(k + 3) * 64 + ct * 4]);
      float4 aa0 = *reinterpret_cast<const float4*>(&a0[k]);
      float4 aa1 = *reinterpret_cast<const float4*>(&a1[k]);
      float4 hh0 = *reinterpret_cast<const float4*>(&h0[k]);
      float4 hh1 = *reinterpret_cast<const float4*>(&h1[k]);
      c0 = f4fma(aa0.x, wl0, c0); c0 = f4fma(aa0.y, wl1, c0);
      c0 = f4fma(aa0.z, wl2, c0); c0 = f4fma(aa0.w, wl3, c0);
      c0 = f4fma(hh0.x, wr0, c0); c0 = f4fma(hh0.y, wr1, c0);
      c0 = f4fma(hh0.z, wr2, c0); c0 = f4fma(hh0.w, wr3, c0);
      c1 = f4fma(aa1.x, wl0, c1); c1 = f4fma(aa1.y, wl1, c1);
      c1 = f4fma(aa1.z, wl2, c1); c1 = f4fma(aa1.w, wl3, c1);
      c1 = f4fma(hh1.x, wr0, c1); c1 = f4fma(hh1.y, wr1, c1);
      c1 = f4fma(hh1.z, wr2, c1); c1 = f4fma(hh1.w, wr3, c1);
    }
    int n0 = r0 + rg * 2;
    if (n0 + 0 < NN) {
      float4 r;
      r.x = eluf(c0.x + bv.x); r.y = eluf(c0.y + bv.y);
      r.z = eluf(c0.z + bv.z); r.w = eluf(c0.w + bv.w);
      *reinterpret_cast<float4*>(&out[(size_t)(n0 + 0) * 64 + ct * 4]) = r;
    }
    if (n0 + 1 < NN) {
      float4 r;
      r.x = eluf(c1.x + bv.x); r.y = eluf(c1.y + bv.y);
      r.z = eluf(c1.z + bv.z); r.w = eluf(c1.w + bv.w);
      *reinterpret_cast<float4*>(&out[(size_t)(n0 + 1) * 64 + ct * 4]) = r;
    }
    __syncthreads();
  }
}

// ---------------------------------------------------------------- pooling
// Wave per 32-node chunk; batch sorted -> in-register accumulate, atomic
// flush on segment change. ~150K f32 atomics to 4096 addresses.
__global__ __launch_bounds__(256) void k_pool2(const float* __restrict__ hs,
                                               const int* __restrict__ batch,
                                               float* __restrict__ g) {
  int cid = (blockIdx.x << 2) + (threadIdx.x >> 6);
  int lane = threadIdx.x & 63;
  int n0 = cid * 32;
  if (n0 >= NN) return;
  int n1 = n0 + 32 < NN ? n0 + 32 : NN;
  int cur = batch[n0];
  float acc = 0.f;
  for (int n = n0; n < n1; ++n) {
    int b = batch[n];
    if (b != cur) {
      atomicAdd(&g[cur * 64 + lane], acc);
      acc = 0.f;
      cur = b;
    }
    acc += hs[(size_t)n * 64 + lane];
  }
  atomicAdd(&g[cur * 64 + lane], acc);
}

// ---------------------------------------------------------------- MLP head
__device__ __forceinline__ int lowerb(const int* __restrict__ a, int n, int key) {
  int lo = 0, hi = n;
  while (lo < hi) { int mid = (lo + hi) >> 1; if (a[mid] < key) lo = mid + 1; else hi = mid; }
  return lo;
}

__global__ __launch_bounds__(256) void k_head(
    const float* __restrict__ g, const int* __restrict__ batch,
    const float* __restrict__ l1W, const float* __restrict__ l1b,
    const float* __restrict__ l2W, const float* __restrict__ l2b,
    const float* __restrict__ telW, const float* __restrict__ telb,
    const float* __restrict__ compW, const float* __restrict__ compb,
    const float* __restrict__ pchW, const float* __restrict__ pchb,
    float* __restrict__ out) {
  __shared__ float gS[4096];
  __shared__ float WS[4096];
  __shared__ float hS[4096];
  __shared__ float invc[64];
  int t = threadIdx.x;
  if (t < 64) {
    int lo = lowerb(batch, NN, t), hi = lowerb(batch, NN, t + 1);
    invc[t] = 1.f / fmaxf((float)(hi - lo), 1.f);
  }
  for (int i = t; i < 4096; i += 256) WS[i] = l1W[i];
  __syncthreads();
  for (int i = t; i < 4096; i += 256) gS[i] = g[i] * invc[i >> 6];
  __syncthreads();
  for (int i = t; i < 4096; i += 256) {
    int r = i >> 6, j = i & 63;
    float s = 0.f;
    for (int k = 0; k < 64; ++k) s += gS[r * 64 + k] * WS[k * 64 + j];
    hS[i] = eluf(s + l1b[j]);
  }
  __syncthreads();
  for (int i = t; i < 4096; i += 256) WS[i] = l2W[i];
  __syncthreads();
  for (int i = t; i < 4096; i += 256) {
    int r = i >> 6, j = i & 63;
    float s = 0.f;
    for (int k = 0; k < 64; ++k) s += hS[r * 64 + k] * WS[k * 64 + j];
    gS[i] = s + l2b[j];
  }
  __syncthreads();
  if (t < 192) {
    int head = t >> 6, r = t & 63;
    const float* Wv = head == 0 ? telW : (head == 1 ? compW : pchW);
    float bb = head == 0 ? telb[0] : (head == 1 ? compb[0] : pchb[0]);
    float s = 0.f;
    for (int k = 0; k < 64; ++k) s += gS[r * 64 + k] * Wv[k];
    out[t] = s + bb;
  }
}

// ---------------------------------------------------------------- launch
extern "C" void kernel_launch(void* const* d_in, const int* in_sizes, int n_in,
                              void* d_out, int out_size, void* d_ws, size_t ws_size,
                              hipStream_t stream) {
  const float* x     = (const float*)d_in[0];
  const int*   eidx  = (const int*)d_in[1];
  const float* eattr = (const float*)d_in[2];
  const int*   batch = (const int*)d_in[3];
  const int*   ntype = (const int*)d_in[4];
  const float* nemb  = (const float*)d_in[5];
  const float* edgeW = (const float*)d_in[6];
  const float* edgeB = (const float*)d_in[7];
  const float* W1    = (const float*)d_in[8];
  const float* atts1 = (const float*)d_in[9];
  const float* attd1 = (const float*)d_in[10];
  const float* We1   = (const float*)d_in[11];
  const float* atte1 = (const float*)d_in[12];
  const float* b1    = (const float*)d_in[13];
  const float* W2    = (const float*)d_in[14];
  const float* atts2 = (const float*)d_in[15];
  const float* attd2 = (const float*)d_in[16];
  const float* We2   = (const float*)d_in[17];
  const float* atte2 = (const float*)d_in[18];
  const float* b2    = (const float*)d_in[19];
  const float* sageWl = (const float*)d_in[20];
  const float* sageWr = (const float*)d_in[21];
  const float* sageB  = (const float*)d_in[22];
  const float* l1W = (const float*)d_in[23];
  const float* l1b = (const float*)d_in[24];
  const float* l2W = (const float*)d_in[25];
  const float* l2b = (const float*)d_in[26];
  const float* telW  = (const float*)d_in[27];
  const float* telb  = (const float*)d_in[28];
  const float* compW = (const float*)d_in[29];
  const float* compb = (const float*)d_in[30];
  const float* pchW  = (const float*)d_in[31];
  const float* pchb  = (const float*)d_in[32];

  char* wp = (char*)d_ws;
  auto alloc = [&](size_t bytes) -> char* {
    char* p = wp;
    wp += (bytes + 255) & ~(size_t)255;
    return p;
  };
  float*  pq      = (float*)alloc(16 * 4);
  int*    cnt     = (int*)alloc((size_t)NN * 4);
  int*    off     = (int*)alloc(((size_t)NN + 1) * 4);
  int*    csr_src = (int*)alloc((size_t)NE * 4);
  float*  csr_ea  = (float*)alloc((size_t)NE * 4);
  float*  as_     = (float*)alloc((size_t)NN * 16);
  float*  ad_     = (float*)alloc((size_t)NN * 16);
  bf16*   hmat    = (bf16*)alloc((size_t)NN * 256 * 2);
  float*  nodeB   = (float*)alloc((size_t)NN * 64 * 4);
  float*  aggbuf  = (float*)alloc((size_t)NN * 64 * 4);
  unsigned short* B1h = (unsigned short*)alloc(256 * 96 * 2);
  unsigned short* B1l = (unsigned short*)alloc(256 * 96 * 2);
  unsigned short* B2h = (unsigned short*)alloc(256 * 64 * 2);
  unsigned short* B2l = (unsigned short*)alloc(256 * 64 * 2);
  // overlaid region R: A1 planes (19.2MB) -> A2 planes (12.8MB) -> sage out
  char* R = alloc((size_t)NN * 96 * 2 * 2);
  unsigned short* A1h = (unsigned short*)R;
  unsigned short* A1l = A1h + (size_t)NN * 96;
  unsigned short* A2h = (unsigned short*)R;
  unsigned short* A2l = A2h + (size_t)NN * 64;
  float* sageout = (float*)R;
  float* gbuf = (float*)alloc(64 * 64 * 4);

  const int* srcI = eidx;
  const int* dstI = eidx + NE;

  hipMemsetAsync(cnt, 0, (size_t)NN * 4, stream);
  hipMemsetAsync(gbuf, 0, 64 * 64 * 4, stream);
  k_pq<<<1, 256, 0, stream>>>(We1, atte1, We2, atte2, edgeW, edgeB, pq);
  k_hist<<<(NE + 255) / 256, 256, 0, stream>>>(dstI, cnt);
  k_scan<<<1, 1024, 0, stream>>>(cnt, off);
  hipMemsetAsync(cnt, 0, (size_t)NN * 4, stream);
  k_scatter<<<(NE + 255) / 256, 256, 0, stream>>>(srcI, dstI, eattr, off, cnt,
                                                  csr_src, csr_ea);
  k_splitW<<<96, 256, 0, stream>>>(W1, W2, B1h, B1l, B2h, B2l);
  k_splitA<<<2048, 256, 0, stream>>>(x, ntype, nemb, A1h, A1l);
  // GAT layer 1
  k_mm_mfma<96><<<(NN + 63) / 64, 256, 0, stream>>>(
      A1h, A1l, B1h, B1l, atts1, attd1, hmat, as_, ad_);
  k_gat<<<NN / 4, 256, 0, stream>>>(off, csr_src, csr_ea, as_, ad_, pq, 0,
                                    hmat, b1, nullptr, A2h, A2l);
  // GAT layer 2
  k_mm_mfma<64><<<(NN + 63) / 64, 256, 0, stream>>>(
      A2h, A2l, B2h, B2l, atts2, attd2, hmat, as_, ad_);
  k_gat<<<NN / 4, 256, 0, stream>>>(off, csr_src, csr_ea, as_, ad_, pq, 8,
                                    hmat, b2, nodeB, nullptr, nullptr);
  // SAGE + pool + head
  k_agg<<<NN / 4, 256, 0, stream>>>(off, csr_src, nodeB, aggbuf);
  k_sage_mm<<<1024, 256, 0, stream>>>(aggbuf, nodeB, sageWl, sageWr, sageB,
                                      sageout);
  k_pool2<<<((NN + 31) / 32 + 3) / 4, 256, 0, stream>>>(sageout, batch, gbuf);
  k_head<<<1, 256, 0, stream>>>(gbuf, batch, l1W, l1b, l2W, l2b, telW, telb,
                                compW, compb, pchW, pchb, (float*)d_out);
}